// Round 2
// baseline (22114.249 us; speedup 1.0000x reference)
//
#include <hip/hip_runtime.h>

#define B_ 64
#define T_ 512
#define I_ 256
#define H_ 1024
#define O_ 256

#define NCLUST 4
#define WPC 64      // workgroups per cluster
#define MB 16       // batches per cluster
#define ROWS 16     // h-rows per WG
#define KTOT 1280   // H_ + I_
#define KPW 320     // K per wave (4 waves)
#define NMF 10      // MFMAs per wave per step

typedef _Float16 f16;
typedef _Float16 f16x2 __attribute__((ext_vector_type(2)));
typedef _Float16 f16x4 __attribute__((ext_vector_type(4)));
typedef _Float16 half8 __attribute__((ext_vector_type(8)));
typedef float floatx4 __attribute__((ext_vector_type(4)));

#if __has_builtin(__builtin_amdgcn_fdot2)
__device__ __forceinline__ float dot2f(f16x2 a, f16x2 b, float c) {
  return __builtin_amdgcn_fdot2(a, b, c, false);
}
#else
__device__ __forceinline__ float dot2f(f16x2 a, f16x2 b, float c) {
  return fmaf((float)a[0], (float)b[0], fmaf((float)a[1], (float)b[1], c));
}
#endif

__device__ __forceinline__ float dot8f(half8 w, half8 v, float acc) {
  acc = dot2f(__builtin_shufflevector(w, w, 0, 1), __builtin_shufflevector(v, v, 0, 1), acc);
  acc = dot2f(__builtin_shufflevector(w, w, 2, 3), __builtin_shufflevector(v, v, 2, 3), acc);
  acc = dot2f(__builtin_shufflevector(w, w, 4, 5), __builtin_shufflevector(v, v, 4, 5), acc);
  acc = dot2f(__builtin_shufflevector(w, w, 6, 7), __builtin_shufflevector(v, v, 6, 7), acc);
  return acc;
}

// ---------- converters ----------

// elementwise fp32 -> f16 (n multiple of 4)
__global__ void cast_f16(const float* __restrict__ src, f16* __restrict__ dst, int n4) {
  int i = blockIdx.x * blockDim.x + threadIdx.x;
  if (i >= n4) return;
  float4 a = reinterpret_cast<const float4*>(src)[i];
  f16x4 v;
  v[0] = (f16)a.x; v[1] = (f16)a.y; v[2] = (f16)a.z; v[3] = (f16)a.w;
  reinterpret_cast<f16x4*>(dst)[i] = v;
}

// src [R][K] fp32 row-major -> dst [K/8][R] of half8 (transposed 8-chunk layout)
__global__ void convert_T8(const float* __restrict__ src, f16* __restrict__ dst,
                           int R, int K) {
  int K8 = K >> 3;
  int total = R * K8;
  int idx = blockIdx.x * blockDim.x + threadIdx.x;
  if (idx >= total) return;
  int r = idx / K8;
  int k8 = idx - r * K8;
  const float4* s = reinterpret_cast<const float4*>(src + (size_t)r * K + (size_t)k8 * 8);
  float4 a = s[0], b = s[1];
  half8 v;
  v[0] = (f16)a.x; v[1] = (f16)a.y; v[2] = (f16)a.z; v[3] = (f16)a.w;
  v[4] = (f16)b.x; v[5] = (f16)b.y; v[6] = (f16)b.z; v[7] = (f16)b.w;
  reinterpret_cast<half8*>(dst)[(size_t)k8 * R + r] = v;
}

// ---------- main recurrent kernel ----------
// grid 256 x block 256. Cluster c = (wg&7)>>1 (keeps a cluster on an XCD pair
// under the usual round-robin mapping; perf-only). WG w in 0..63 owns h-rows
// [w*16, w*16+16). Weights stationary in VGPRs; h exchanged via global with
// per-step release/acquire counters; double-buffered h (WAR-safe: cnt[s-1]==64
// implies h[s-2] fully consumed).
__global__ __launch_bounds__(256) void rnn_mfma(
    const f16* __restrict__ whh,   // [H][H] f16 row-major
    const f16* __restrict__ wih,   // [H][I] f16 row-major
    const f16* __restrict__ xbf,   // [B][T][I] f16
    const float* __restrict__ bih,
    const float* __restrict__ bhh,
    f16* __restrict__ hbuf,        // [NCLUST][2][MB][H] f16 (zeroed buf0 = h0)
    int* __restrict__ cnt)         // [NCLUST][T+1] int (zeroed)
{
  const int wg = blockIdx.x;
  const int c = (wg & 7) >> 1;
  const int w = ((wg >> 3) << 1) | (wg & 1);
  const int tid = threadIdx.x;
  const int wv = tid >> 6;
  const int l = tid & 63;
  const int lr = l & 15;   // A: batch-in-cluster; B: row-in-slice
  const int kb = l >> 4;   // k-subblock (0..3), 8 elems each
  const int n0 = w * ROWS;
  const int b0 = c * MB;

  // --- preload B-fragments (weights) into registers: W'[n][k], k = wv*320 + i*32 + kb*8
  half8 bf[NMF];
#pragma unroll
  for (int i = 0; i < NMF; ++i) {
    int k = wv * KPW + i * 32 + kb * 8;
    int n = n0 + lr;
    if (k < H_) bf[i] = *reinterpret_cast<const half8*>(&whh[(size_t)n * H_ + k]);
    else        bf[i] = *reinterpret_cast<const half8*>(&wih[(size_t)n * I_ + (k - H_)]);
  }
  const float bias = bih[n0 + (tid & 15)] + bhh[n0 + (tid & 15)];

  __shared__ floatx4 red[4][64];

  f16* hc = hbuf + (size_t)(c * 2) * MB * H_;   // this cluster's 2 h buffers
  int* cc = cnt + c * (T_ + 1);

  for (int s = 1; s <= T_; ++s) {
    // --- wait for h[s-1] published by all 64 cluster WGs
    if (s > 1) {
      int g = 0;
      while (__hip_atomic_load(&cc[s - 1], __ATOMIC_ACQUIRE, __HIP_MEMORY_SCOPE_AGENT) < WPC) {
        if (++g > (1 << 22)) break;  // safety valve: fail validation, don't hang
      }
    }
    const f16* hr = hc + (size_t)((s - 1) & 1) * MB * H_;

    // --- compute: D[m=batch][n=row] += A(h/x) x B(W')
    floatx4 acc0 = {0.f, 0.f, 0.f, 0.f}, acc1 = {0.f, 0.f, 0.f, 0.f};
#pragma unroll
    for (int i = 0; i < NMF; ++i) {
      int k = wv * KPW + i * 32 + kb * 8;
      half8 af;
      if (k < H_) af = *reinterpret_cast<const half8*>(&hr[(size_t)lr * H_ + k]);
      else        af = *reinterpret_cast<const half8*>(
                        &xbf[((size_t)(b0 + lr) * T_ + (s - 1)) * I_ + (k - H_)]);
      if (i & 1) acc1 = __builtin_amdgcn_mfma_f32_16x16x32_f16(af, bf[i], acc1, 0, 0, 0);
      else       acc0 = __builtin_amdgcn_mfma_f32_16x16x32_f16(af, bf[i], acc0, 0, 0, 0);
    }
    floatx4 acc = acc0 + acc1;

    // --- reduce 4 K-split partials via LDS
    red[wv][l] = acc;
    __syncthreads();
    {
      int l2 = tid & 63, r = tid >> 6;
      float v = red[0][l2][r] + red[1][l2][r] + red[2][l2][r] + red[3][l2][r];
      v += bias;
      float hn = tanhf(v);
      int m = ((l2 >> 4) << 2) | r;      // batch-in-cluster (C/D row)
      int n = n0 + (l2 & 15);            // global h row (C/D col)
      f16* hw = hc + (size_t)(s & 1) * MB * H_;
      hw[(size_t)m * H_ + n] = (f16)hn;
    }
    __threadfence();
    __syncthreads();   // also protects `red` reuse next iteration
    if (tid == 0)
      __hip_atomic_fetch_add(&cc[s], 1, __ATOMIC_RELEASE, __HIP_MEMORY_SCOPE_AGENT);
  }
}

// ---------- FC head ----------
// out[b][o] = h_last[b] . W_fc[o] + b_fc[o]; h_last = hbuf[c][0][m] (T_ even)
__global__ __launch_bounds__(256) void fc_head(
    const f16* __restrict__ hbuf, const f16* __restrict__ wfcT,
    const float* __restrict__ bfc, float* __restrict__ out) {
  __shared__ f16 hs[H_];
  const int b = blockIdx.x;
  const int c = b / MB, m = b % MB;
  const f16* hrow = hbuf + ((size_t)(c * 2) * MB + m) * H_;
  const int o = threadIdx.x;
  reinterpret_cast<f16x4*>(hs)[o] = reinterpret_cast<const f16x4*>(hrow)[o];
  __syncthreads();
  float acc = bfc[o];
  const half8* wp = reinterpret_cast<const half8*>(wfcT) + o;
  const half8* hv = reinterpret_cast<const half8*>(hs);
#pragma unroll 8
  for (int c8 = 0; c8 < H_ / 8; ++c8) acc = dot8f(wp[(size_t)c8 * O_], hv[c8], acc);
  out[(size_t)b * O_ + o] = acc;
}

// ---------- round-1 fallback (known-good, weight-streaming) ----------
__global__ __launch_bounds__(1024) void rnn_f16(
    const float* __restrict__ x, const f16* __restrict__ wihT,
    const f16* __restrict__ whhT, const float* __restrict__ bih,
    const float* __restrict__ bhh, const f16* __restrict__ wfcT,
    const float* __restrict__ bfc, float* __restrict__ out) {
  __shared__ f16 hs[H_];
  __shared__ f16 xs[I_];
  const int b = blockIdx.x;
  const int j = threadIdx.x;
  const float bias = bih[j] + bhh[j];
  hs[j] = (f16)0.f;
  const half8* wih_p = reinterpret_cast<const half8*>(wihT) + j;
  const half8* whh_p = reinterpret_cast<const half8*>(whhT) + j;
  const half8* xv = reinterpret_cast<const half8*>(xs);
  const half8* hv = reinterpret_cast<const half8*>(hs);
  const float* xrow = x + (size_t)b * T_ * I_;
  for (int t = 0; t < T_; ++t) {
    if (j < I_) xs[j] = (f16)xrow[t * I_ + j];
    __syncthreads();
    float acc = bias;
#pragma unroll 8
    for (int c = 0; c < I_ / 8; ++c) acc = dot8f(wih_p[c * H_], xv[c], acc);
#pragma unroll 8
    for (int c = 0; c < H_ / 8; ++c) acc = dot8f(whh_p[c * H_], hv[c], acc);
    float hn = tanhf(acc);
    __syncthreads();
    hs[j] = (f16)hn;
  }
  __syncthreads();
  if (j < O_) {
    const half8* wfc_p = reinterpret_cast<const half8*>(wfcT) + j;
    float acc = bfc[j];
#pragma unroll 8
    for (int c = 0; c < H_ / 8; ++c) acc = dot8f(wfc_p[c * O_], hv[c], acc);
    out[(size_t)b * O_ + j] = acc;
  }
}

extern "C" void kernel_launch(void* const* d_in, const int* in_sizes, int n_in,
                              void* d_out, int out_size, void* d_ws, size_t ws_size,
                              hipStream_t stream) {
  const float* x   = (const float*)d_in[0];
  const float* Wih = (const float*)d_in[1];
  const float* Whh = (const float*)d_in[2];
  const float* bih = (const float*)d_in[3];
  const float* bhh = (const float*)d_in[4];
  const float* Wfc = (const float*)d_in[5];
  const float* bfc = (const float*)d_in[6];
  float* out = (float*)d_out;

  const size_t n_whh = (size_t)H_ * H_;
  const size_t n_wih = (size_t)H_ * I_;
  const size_t n_wfc = (size_t)O_ * H_;
  const size_t n_x   = (size_t)B_ * T_ * I_;
  const size_t n_h   = (size_t)NCLUST * 2 * MB * H_;
  const size_t n_cnt = (size_t)NCLUST * (T_ + 1);

  // ws layout (f16 elements then ints), 16B-aligned sections
  size_t off = 0;
  const size_t o_whh = off; off += n_whh;          // f16
  const size_t o_wih = off; off += n_wih;
  const size_t o_wfc = off; off += n_wfc;
  const size_t o_x   = off; off += n_x;
  const size_t o_h   = off; off += n_h;
  size_t bytes_f16 = off * sizeof(f16);
  bytes_f16 = (bytes_f16 + 255) & ~(size_t)255;
  const size_t o_cnt_b = bytes_f16;
  const size_t need = o_cnt_b + n_cnt * sizeof(int);

  const int thr = 256;
  if (ws_size >= need) {
    f16* wsf = (f16*)d_ws;
    f16* whh_h = wsf + o_whh;
    f16* wih_h = wsf + o_wih;
    f16* wfcT  = wsf + o_wfc;
    f16* xbf   = wsf + o_x;
    f16* hbuf  = wsf + o_h;
    int* cnt   = (int*)((char*)d_ws + o_cnt_b);

    // zero h0 buffers + counters (every launch: graph-replay safe)
    hipMemsetAsync(hbuf, 0, n_h * sizeof(f16), stream);
    hipMemsetAsync(cnt, 0, n_cnt * sizeof(int), stream);

    cast_f16<<<(int)(n_whh / 4 + thr - 1) / thr, thr, 0, stream>>>(Whh, whh_h, (int)(n_whh / 4));
    cast_f16<<<(int)(n_wih / 4 + thr - 1) / thr, thr, 0, stream>>>(Wih, wih_h, (int)(n_wih / 4));
    cast_f16<<<(int)(n_x / 4 + thr - 1) / thr, thr, 0, stream>>>(x, xbf, (int)(n_x / 4));
    convert_T8<<<(int)(n_wfc / 8 + thr - 1) / thr, thr, 0, stream>>>(Wfc, wfcT, O_, H_);

    rnn_mfma<<<NCLUST * WPC, 256, 0, stream>>>(whh_h, wih_h, xbf, bih, bhh, hbuf, cnt);
    fc_head<<<B_, O_, 0, stream>>>(hbuf, wfcT, bfc, out);
  } else {
    // fallback: round-1 path (needs 3 MB)
    f16* wihT = (f16*)d_ws;
    f16* whhT = wihT + n_wih;
    f16* wfcT = whhT + n_whh;
    convert_T8<<<(int)(n_wih / 8 + thr - 1) / thr, thr, 0, stream>>>(Wih, wihT, H_, I_);
    convert_T8<<<(int)(n_whh / 8 + thr - 1) / thr, thr, 0, stream>>>(Whh, whhT, H_, H_);
    convert_T8<<<(int)(n_wfc / 8 + thr - 1) / thr, thr, 0, stream>>>(Wfc, wfcT, O_, H_);
    rnn_f16<<<B_, 1024, 0, stream>>>(x, wihT, whhT, bih, bhh, wfcT, bfc, out);
  }
}

// Round 3
// 4359.340 us; speedup vs baseline: 5.0728x; 5.0728x over previous
//
#include <hip/hip_runtime.h>

#define B_ 64
#define T_ 512
#define I_ 256
#define H_ 1024
#define O_ 256

#define NCLUST 4
#define WPC 64       // workgroups per cluster
#define MB 16        // batches per cluster
#define ROWS 16      // h-rows per WG
#define KPW 256      // K per wave (4 waves, K=H)
#define NMF 8        // MFMAs per wave per step
#define CSTRIDE 640  // ints per cluster's counter block (cacheline-padded)

typedef _Float16 f16;
typedef _Float16 f16x2 __attribute__((ext_vector_type(2)));
typedef _Float16 f16x4 __attribute__((ext_vector_type(4)));
typedef _Float16 half8 __attribute__((ext_vector_type(8)));
typedef float floatx4 __attribute__((ext_vector_type(4)));
typedef unsigned int uint4v __attribute__((ext_vector_type(4)));

// ---------- cache-bypass (coherence-point) access helpers ----------
// sc0 sc1 => bypass L1/L2, access at device coherence point (MALL).
__device__ __forceinline__ uint4v load_uc16(const void* p) {
  uint4v r;
  asm volatile("global_load_dwordx4 %0, %1, off sc0 sc1" : "=v"(r) : "v"(p));
  return r;
}
__device__ __forceinline__ void store_uc4(void* p, unsigned v) {
  asm volatile("global_store_dword %0, %1, off sc0 sc1" :: "v"(p), "v"(v) : "memory");
}
__device__ __forceinline__ unsigned pack_f16x2(float a, float b) {
  f16x2 t; t[0] = (f16)a; t[1] = (f16)b;
  return __builtin_bit_cast(unsigned, t);
}

#if __has_builtin(__builtin_amdgcn_fdot2)
__device__ __forceinline__ float dot2f(f16x2 a, f16x2 b, float c) {
  return __builtin_amdgcn_fdot2(a, b, c, false);
}
#else
__device__ __forceinline__ float dot2f(f16x2 a, f16x2 b, float c) {
  return fmaf((float)a[0], (float)b[0], fmaf((float)a[1], (float)b[1], c));
}
#endif

__device__ __forceinline__ float dot8f(half8 w, half8 v, float acc) {
  acc = dot2f(__builtin_shufflevector(w, w, 0, 1), __builtin_shufflevector(v, v, 0, 1), acc);
  acc = dot2f(__builtin_shufflevector(w, w, 2, 3), __builtin_shufflevector(v, v, 2, 3), acc);
  acc = dot2f(__builtin_shufflevector(w, w, 4, 5), __builtin_shufflevector(v, v, 4, 5), acc);
  acc = dot2f(__builtin_shufflevector(w, w, 6, 7), __builtin_shufflevector(v, v, 6, 7), acc);
  return acc;
}

// ---------- converters ----------
__global__ void cast_f16(const float* __restrict__ src, f16* __restrict__ dst, int n4) {
  int i = blockIdx.x * blockDim.x + threadIdx.x;
  if (i >= n4) return;
  float4 a = reinterpret_cast<const float4*>(src)[i];
  f16x4 v;
  v[0] = (f16)a.x; v[1] = (f16)a.y; v[2] = (f16)a.z; v[3] = (f16)a.w;
  reinterpret_cast<f16x4*>(dst)[i] = v;
}

// src [R][K] fp32 row-major -> dst [K/8][R] of half8
__global__ void convert_T8(const float* __restrict__ src, f16* __restrict__ dst,
                           int R, int K) {
  int K8 = K >> 3;
  int total = R * K8;
  int idx = blockIdx.x * blockDim.x + threadIdx.x;
  if (idx >= total) return;
  int r = idx / K8;
  int k8 = idx - r * K8;
  const float4* s = reinterpret_cast<const float4*>(src + (size_t)r * K + (size_t)k8 * 8);
  float4 a = s[0], b = s[1];
  half8 v;
  v[0] = (f16)a.x; v[1] = (f16)a.y; v[2] = (f16)a.z; v[3] = (f16)a.w;
  v[4] = (f16)b.x; v[5] = (f16)b.y; v[6] = (f16)b.z; v[7] = (f16)b.w;
  reinterpret_cast<half8*>(dst)[(size_t)k8 * R + r] = v;
}

// zero the sync counters (kernel, not SDMA memset, so later atomics see it safely)
__global__ void init_cnt(int* __restrict__ cnt) {
  for (int i = threadIdx.x; i < NCLUST * CSTRIDE; i += blockDim.x) cnt[i] = 0;
}

// ---------- xp = x @ W_ih^T + (b_ih + b_hh), stored [T][B][H] f16 ----------
// grid: 512 m-tiles (rows g = b*T + t of x) x 16 n-tiles, 256 thr (4 waves).
__global__ __launch_bounds__(256) void xp_gemm(
    const float* __restrict__ x,   // [B][T][I] fp32
    const f16* __restrict__ wih,   // [H][I] f16
    const float* __restrict__ bih,
    const float* __restrict__ bhh,
    f16* __restrict__ xp) {        // [T][B][H] f16
  const int wg = blockIdx.x;
  const int mt = wg >> 4;
  const int nt = wg & 15;
  const int wv = threadIdx.x >> 6;
  const int lane = threadIdx.x & 63;
  const int lr = lane & 15;
  const int kb = lane >> 4;
  const int m0 = mt * 64 + wv * 16;
  const int n0 = nt * 64;

  const float* xrow = x + (size_t)(m0 + lr) * I_;
  half8 af[8];
#pragma unroll
  for (int ks = 0; ks < 8; ++ks) {
    const float4* p = reinterpret_cast<const float4*>(xrow + ks * 32 + kb * 8);
    float4 a = p[0], b = p[1];
    half8 v;
    v[0] = (f16)a.x; v[1] = (f16)a.y; v[2] = (f16)a.z; v[3] = (f16)a.w;
    v[4] = (f16)b.x; v[5] = (f16)b.y; v[6] = (f16)b.z; v[7] = (f16)b.w;
    af[ks] = v;
  }

#pragma unroll
  for (int ns = 0; ns < 4; ++ns) {
    const int nrow = n0 + ns * 16;
    const f16* wrow = wih + (size_t)(nrow + lr) * I_;
    floatx4 acc = {0.f, 0.f, 0.f, 0.f};
#pragma unroll
    for (int ks = 0; ks < 8; ++ks) {
      half8 bfr = *reinterpret_cast<const half8*>(wrow + ks * 32 + kb * 8);
      acc = __builtin_amdgcn_mfma_f32_16x16x32_f16(af[ks], bfr, acc, 0, 0, 0);
    }
    const int n = nrow + lr;                 // D col = lane&15
    const float bias = bih[n] + bhh[n];
#pragma unroll
    for (int r = 0; r < 4; ++r) {
      const int gm = m0 + (lane >> 4) * 4 + r;   // D row
      const int b = gm >> 9;                      // / T_
      const int t = gm & (T_ - 1);
      float v = acc[r] + bias;
      float po = __shfl_xor(v, 1);
      if (!(lane & 1)) {
        *reinterpret_cast<unsigned*>(xp + (size_t)(t * B_ + b) * H_ + n) =
            pack_f16x2(v, po);
      }
    }
  }
}

// ---------- recurrent kernel ----------
// grid 256 x 256 thr. cluster c = wg&3 owns batches [c*16,c*16+16);
// WG w = wg>>2 owns h rows [w*16,w*16+16). W_hh stationary in VGPRs.
// h exchanged via MALL (sc0/sc1 bypass); per-step counter sync.
__global__ __launch_bounds__(256) void rnn2(
    const f16* __restrict__ whh,   // [H][H] f16
    const f16* __restrict__ xp,    // [T][B][H] f16 (biases folded in)
    f16* __restrict__ hbuf,        // [NCLUST][2][MB][H] f16
    int* __restrict__ cnt) {       // [NCLUST][CSTRIDE]
  const int wg = blockIdx.x;
  const int c = wg & 3;
  const int w = wg >> 2;
  const int tid = threadIdx.x;
  const int wv = tid >> 6;
  const int lane = tid & 63;
  const int lr = lane & 15;
  const int kb = lane >> 4;
  const int n0 = w * ROWS;

  // stationary B-fragments: W_hh[n0+lr][wv*256 + i*32 + kb*8 ..+8]
  half8 bf[NMF];
#pragma unroll
  for (int i = 0; i < NMF; ++i) {
    const int k = wv * KPW + i * 32 + kb * 8;
    bf[i] = *reinterpret_cast<const half8*>(&whh[(size_t)(n0 + lr) * H_ + k]);
  }

  // reduce-role mapping (validated in round 2): this thread owns output (m, n0+nl)
  const int m = ((lane >> 4) << 2) | wv;
  const int nl = lane & 15;
  const f16* xq = xp + (size_t)(c * MB + m) * H_ + n0 + nl;

  __shared__ floatx4 red[4][64];
  f16* hc = hbuf + (size_t)c * 2 * MB * H_;
  int* cc = cnt + c * CSTRIDE;

  for (int s = 1; s <= T_; ++s) {
    // prefetch this step's xp value (regular cached load; overlaps the poll)
    float xpv = (float)xq[(size_t)(s - 1) * (B_ * H_)];

    if (s > 1) {
      if (tid == 0) {
        int g = 0;
        while (__hip_atomic_load(&cc[s - 1], __ATOMIC_RELAXED,
                                 __HIP_MEMORY_SCOPE_AGENT) < WPC) {
          if (++g > (1 << 17)) break;  // fail-fast valve (validation will catch)
        }
        (void)__hip_atomic_load(&cc[s - 1], __ATOMIC_ACQUIRE,
                                __HIP_MEMORY_SCOPE_AGENT);
      }
      __syncthreads();
    }

    floatx4 acc0 = {0.f, 0.f, 0.f, 0.f}, acc1 = {0.f, 0.f, 0.f, 0.f};
    if (s > 1) {
      const f16* hr = hc + (size_t)((s - 1) & 1) * MB * H_;
      uint4v af[NMF];
#pragma unroll
      for (int i = 0; i < NMF; ++i) {
        const int k = wv * KPW + i * 32 + kb * 8;
        af[i] = load_uc16(&hr[(size_t)lr * H_ + k]);
      }
      asm volatile("s_waitcnt vmcnt(0)" ::: "memory");
      __builtin_amdgcn_sched_barrier(0);
#pragma unroll
      for (int i = 0; i < NMF; ++i) {
        half8 a = __builtin_bit_cast(half8, af[i]);
        if (i & 1) acc1 = __builtin_amdgcn_mfma_f32_16x16x32_f16(a, bf[i], acc1, 0, 0, 0);
        else       acc0 = __builtin_amdgcn_mfma_f32_16x16x32_f16(a, bf[i], acc0, 0, 0, 0);
      }
    }

    red[wv][lane] = acc0 + acc1;
    __syncthreads();

    // K-split reduce + tanh; pair-pack and publish h[s] through MALL
    float v = red[0][lane][wv] + red[1][lane][wv] + red[2][lane][wv] +
              red[3][lane][wv] + xpv;
    float hn = tanhf(v);
    float po = __shfl_xor(hn, 1);
    f16* hw = hc + (size_t)(s & 1) * MB * H_;
    if (!(lane & 1)) {
      store_uc4(&hw[(size_t)m * H_ + n0 + nl], pack_f16x2(hn, po));
    }
    asm volatile("s_waitcnt vmcnt(0)" ::: "memory");  // this wave's stores acked
    __syncthreads();                                   // all waves drained
    if (tid == 0)
      __hip_atomic_fetch_add(&cc[s], 1, __ATOMIC_RELEASE, __HIP_MEMORY_SCOPE_AGENT);
  }
}

// ---------- FC head ----------
__global__ __launch_bounds__(256) void fc_head(
    const f16* __restrict__ hbuf, const f16* __restrict__ wfcT,
    const float* __restrict__ bfc, float* __restrict__ out) {
  __shared__ f16 hs[H_];
  const int b = blockIdx.x;
  const int c = b / MB, m = b % MB;
  const f16* hrow = hbuf + ((size_t)(c * 2) * MB + m) * H_;  // T_ even -> buffer 0
  const int o = threadIdx.x;
  reinterpret_cast<f16x4*>(hs)[o] = reinterpret_cast<const f16x4*>(hrow)[o];
  __syncthreads();
  float acc = bfc[o];
  const half8* wp = reinterpret_cast<const half8*>(wfcT) + o;
  const half8* hv = reinterpret_cast<const half8*>(hs);
#pragma unroll 8
  for (int c8 = 0; c8 < H_ / 8; ++c8) acc = dot8f(wp[(size_t)c8 * O_], hv[c8], acc);
  out[(size_t)b * O_ + o] = acc;
}

// ---------- round-1 fallback (weight-streaming, 3 MB ws) ----------
__global__ __launch_bounds__(1024) void rnn_f16(
    const float* __restrict__ x, const f16* __restrict__ wihT,
    const f16* __restrict__ whhT, const float* __restrict__ bih,
    const float* __restrict__ bhh, const f16* __restrict__ wfcT,
    const float* __restrict__ bfc, float* __restrict__ out) {
  __shared__ f16 hs[H_];
  __shared__ f16 xs[I_];
  const int b = blockIdx.x;
  const int j = threadIdx.x;
  const float bias = bih[j] + bhh[j];
  hs[j] = (f16)0.f;
  const half8* wih_p = reinterpret_cast<const half8*>(wihT) + j;
  const half8* whh_p = reinterpret_cast<const half8*>(whhT) + j;
  const half8* xv = reinterpret_cast<const half8*>(xs);
  const half8* hv = reinterpret_cast<const half8*>(hs);
  const float* xrow = x + (size_t)b * T_ * I_;
  for (int t = 0; t < T_; ++t) {
    if (j < I_) xs[j] = (f16)xrow[t * I_ + j];
    __syncthreads();
    float acc = bias;
#pragma unroll 8
    for (int c = 0; c < I_ / 8; ++c) acc = dot8f(wih_p[c * H_], xv[c], acc);
#pragma unroll 8
    for (int c = 0; c < H_ / 8; ++c) acc = dot8f(whh_p[c * H_], hv[c], acc);
    float hn = tanhf(acc);
    __syncthreads();
    hs[j] = (f16)hn;
  }
  __syncthreads();
  if (j < O_) {
    const half8* wfc_p = reinterpret_cast<const half8*>(wfcT) + j;
    float acc = bfc[j];
#pragma unroll 8
    for (int c = 0; c < H_ / 8; ++c) acc = dot8f(wfc_p[c * O_], hv[c], acc);
    out[(size_t)b * O_ + j] = acc;
  }
}

// ---------- fp32 fallback (0 ws) ----------
__global__ __launch_bounds__(1024) void rnn_fp32(
    const float* __restrict__ x,
    const float* __restrict__ Wih, const float* __restrict__ Whh,
    const float* __restrict__ bih, const float* __restrict__ bhh,
    const float* __restrict__ Wfc, const float* __restrict__ bfc,
    float* __restrict__ out) {
  __shared__ float hs[H_];
  __shared__ float xs[I_];
  const int b = blockIdx.x;
  const int j = threadIdx.x;
  const float bias = bih[j] + bhh[j];
  hs[j] = 0.f;
  const float4* wih_r = reinterpret_cast<const float4*>(Wih + (size_t)j * I_);
  const float4* whh_r = reinterpret_cast<const float4*>(Whh + (size_t)j * H_);
  const float4* xv = reinterpret_cast<const float4*>(xs);
  const float4* hv = reinterpret_cast<const float4*>(hs);
  const float* xrow = x + (size_t)b * T_ * I_;
  for (int t = 0; t < T_; ++t) {
    if (j < I_) xs[j] = xrow[t * I_ + j];
    __syncthreads();
    float acc = bias;
#pragma unroll 4
    for (int c = 0; c < I_ / 4; ++c) {
      float4 w = wih_r[c], v = xv[c];
      acc = fmaf(w.x, v.x, acc); acc = fmaf(w.y, v.y, acc);
      acc = fmaf(w.z, v.z, acc); acc = fmaf(w.w, v.w, acc);
    }
#pragma unroll 4
    for (int c = 0; c < H_ / 4; ++c) {
      float4 w = whh_r[c], v = hv[c];
      acc = fmaf(w.x, v.x, acc); acc = fmaf(w.y, v.y, acc);
      acc = fmaf(w.z, v.z, acc); acc = fmaf(w.w, v.w, acc);
    }
    float hn = tanhf(acc);
    __syncthreads();
    hs[j] = hn;
  }
  __syncthreads();
  if (j < O_) {
    float acc = bfc[j];
    const float4* wfc_r = reinterpret_cast<const float4*>(Wfc + (size_t)j * H_);
    for (int c = 0; c < H_ / 4; ++c) {
      float4 w = wfc_r[c], v = hv[c];
      acc = fmaf(w.x, v.x, acc); acc = fmaf(w.y, v.y, acc);
      acc = fmaf(w.z, v.z, acc); acc = fmaf(w.w, v.w, acc);
    }
    out[(size_t)b * O_ + j] = acc;
  }
}

extern "C" void kernel_launch(void* const* d_in, const int* in_sizes, int n_in,
                              void* d_out, int out_size, void* d_ws, size_t ws_size,
                              hipStream_t stream) {
  const float* x   = (const float*)d_in[0];
  const float* Wih = (const float*)d_in[1];
  const float* Whh = (const float*)d_in[2];
  const float* bih = (const float*)d_in[3];
  const float* bhh = (const float*)d_in[4];
  const float* Wfc = (const float*)d_in[5];
  const float* bfc = (const float*)d_in[6];
  float* out = (float*)d_out;

  const size_t n_whh = (size_t)H_ * H_;
  const size_t n_wih = (size_t)H_ * I_;
  const size_t n_wfc = (size_t)O_ * H_;
  const size_t n_xp  = (size_t)T_ * B_ * H_;
  const size_t n_h   = (size_t)NCLUST * 2 * MB * H_;

  size_t off = 0;
  const size_t o_whh = off; off += n_whh;
  const size_t o_wih = off; off += n_wih;
  const size_t o_wfc = off; off += n_wfc;
  const size_t o_xp  = off; off += n_xp;
  const size_t o_h   = off; off += n_h;
  size_t bytes_f16 = off * sizeof(f16);
  bytes_f16 = (bytes_f16 + 255) & ~(size_t)255;
  const size_t need_full = bytes_f16 + (size_t)NCLUST * CSTRIDE * sizeof(int);

  const int thr = 256;
  if (ws_size >= need_full) {
    f16* wsf   = (f16*)d_ws;
    f16* whh_h = wsf + o_whh;
    f16* wih_h = wsf + o_wih;
    f16* wfcT  = wsf + o_wfc;
    f16* xpb   = wsf + o_xp;
    f16* hbuf  = wsf + o_h;
    int* cnt   = (int*)((char*)d_ws + bytes_f16);

    init_cnt<<<1, 256, 0, stream>>>(cnt);
    cast_f16<<<(int)(n_whh / 4 / thr), thr, 0, stream>>>(Whh, whh_h, (int)(n_whh / 4));
    cast_f16<<<(int)(n_wih / 4 / thr), thr, 0, stream>>>(Wih, wih_h, (int)(n_wih / 4));
    convert_T8<<<(int)(n_wfc / 8 / thr), thr, 0, stream>>>(Wfc, wfcT, O_, H_);
    xp_gemm<<<(T_ * B_ / 64) * (H_ / 64), thr, 0, stream>>>(x, wih_h, bih, bhh, xpb);
    rnn2<<<NCLUST * WPC, thr, 0, stream>>>(whh_h, xpb, hbuf, cnt);
    fc_head<<<B_, O_, 0, stream>>>(hbuf, wfcT, bfc, out);
  } else if (ws_size >= (n_wih + n_whh + n_wfc) * sizeof(f16)) {
    f16* wihT = (f16*)d_ws;
    f16* whhT = wihT + n_wih;
    f16* wfcT = whhT + n_whh;
    convert_T8<<<(int)((n_wih / 8 + thr - 1) / thr), thr, 0, stream>>>(Wih, wihT, H_, I_);
    convert_T8<<<(int)((n_whh / 8 + thr - 1) / thr), thr, 0, stream>>>(Whh, whhT, H_, H_);
    convert_T8<<<(int)((n_wfc / 8 + thr - 1) / thr), thr, 0, stream>>>(Wfc, wfcT, O_, H_);
    rnn_f16<<<B_, 1024, 0, stream>>>(x, wihT, whhT, bih, bhh, wfcT, bfc, out);
  } else {
    rnn_fp32<<<B_, 1024, 0, stream>>>(x, Wih, Whh, bih, bhh, Wfc, bfc, out);
  }
}

// Round 4
// 2152.496 us; speedup vs baseline: 10.2738x; 2.0252x over previous
//
#include <hip/hip_runtime.h>

#define B_ 64
#define T_ 512
#define I_ 256
#define H_ 1024
#define O_ 256

#define NCLUST 4
#define WPC 64        // workgroups per cluster
#define MB 16         // batches per cluster
#define ROWS 16       // h-rows per WG
#define KPW 256       // K per wave (4 waves, K=H)
#define NMF 8         // MFMAs per wave per step
#define FSTRIDE 256   // ints per cluster flag block (4 groups x 32-int lines, padded)

typedef _Float16 f16;
typedef _Float16 f16x2 __attribute__((ext_vector_type(2)));
typedef _Float16 f16x4 __attribute__((ext_vector_type(4)));
typedef _Float16 half8 __attribute__((ext_vector_type(8)));
typedef float floatx4 __attribute__((ext_vector_type(4)));
typedef unsigned int uint4v __attribute__((ext_vector_type(4)));

// ---------- cache-bypass (coherence-point) access helpers ----------
__device__ __forceinline__ uint4v load_uc16(const void* p) {
  uint4v r;
  asm volatile("global_load_dwordx4 %0, %1, off sc0 sc1" : "=v"(r) : "v"(p));
  return r;
}
__device__ __forceinline__ int load_uc4(const void* p) {
  int r;
  asm volatile("global_load_dword %0, %1, off sc0 sc1" : "=v"(r) : "v"(p));
  return r;
}
__device__ __forceinline__ void store_uc4(void* p, unsigned v) {
  asm volatile("global_store_dword %0, %1, off sc0 sc1" :: "v"(p), "v"(v) : "memory");
}
__device__ __forceinline__ unsigned pack_f16x2(float a, float b) {
  f16x2 t; t[0] = (f16)a; t[1] = (f16)b;
  return __builtin_bit_cast(unsigned, t);
}

#if __has_builtin(__builtin_amdgcn_fdot2)
__device__ __forceinline__ float dot2f(f16x2 a, f16x2 b, float c) {
  return __builtin_amdgcn_fdot2(a, b, c, false);
}
#else
__device__ __forceinline__ float dot2f(f16x2 a, f16x2 b, float c) {
  return fmaf((float)a[0], (float)b[0], fmaf((float)a[1], (float)b[1], c));
}
#endif

__device__ __forceinline__ float dot8f(half8 w, half8 v, float acc) {
  acc = dot2f(__builtin_shufflevector(w, w, 0, 1), __builtin_shufflevector(v, v, 0, 1), acc);
  acc = dot2f(__builtin_shufflevector(w, w, 2, 3), __builtin_shufflevector(v, v, 2, 3), acc);
  acc = dot2f(__builtin_shufflevector(w, w, 4, 5), __builtin_shufflevector(v, v, 4, 5), acc);
  acc = dot2f(__builtin_shufflevector(w, w, 6, 7), __builtin_shufflevector(v, v, 6, 7), acc);
  return acc;
}

// ---------- converters ----------
__global__ void cast_f16(const float* __restrict__ src, f16* __restrict__ dst, int n4) {
  int i = blockIdx.x * blockDim.x + threadIdx.x;
  if (i >= n4) return;
  float4 a = reinterpret_cast<const float4*>(src)[i];
  f16x4 v;
  v[0] = (f16)a.x; v[1] = (f16)a.y; v[2] = (f16)a.z; v[3] = (f16)a.w;
  reinterpret_cast<f16x4*>(dst)[i] = v;
}

__global__ void convert_T8(const float* __restrict__ src, f16* __restrict__ dst,
                           int R, int K) {
  int K8 = K >> 3;
  int total = R * K8;
  int idx = blockIdx.x * blockDim.x + threadIdx.x;
  if (idx >= total) return;
  int r = idx / K8;
  int k8 = idx - r * K8;
  const float4* s = reinterpret_cast<const float4*>(src + (size_t)r * K + (size_t)k8 * 8);
  float4 a = s[0], b = s[1];
  half8 v;
  v[0] = (f16)a.x; v[1] = (f16)a.y; v[2] = (f16)a.z; v[3] = (f16)a.w;
  v[4] = (f16)b.x; v[5] = (f16)b.y; v[6] = (f16)b.z; v[7] = (f16)b.w;
  reinterpret_cast<half8*>(dst)[(size_t)k8 * R + r] = v;
}

__global__ void init_flags(int* __restrict__ flags) {
  for (int i = threadIdx.x; i < NCLUST * FSTRIDE; i += blockDim.x) flags[i] = 0;
}

// ---------- xp = x @ W_ih^T + (b_ih + b_hh), stored [T][B][H] f16 ----------
__global__ __launch_bounds__(256) void xp_gemm(
    const float* __restrict__ x,   // [B][T][I] fp32
    const f16* __restrict__ wih,   // [H][I] f16
    const float* __restrict__ bih,
    const float* __restrict__ bhh,
    f16* __restrict__ xp) {        // [T][B][H] f16
  const int wg = blockIdx.x;
  const int mt = wg >> 4;
  const int nt = wg & 15;
  const int wv = threadIdx.x >> 6;
  const int lane = threadIdx.x & 63;
  const int lr = lane & 15;
  const int kb = lane >> 4;
  const int m0 = mt * 64 + wv * 16;
  const int n0 = nt * 64;

  const float* xrow = x + (size_t)(m0 + lr) * I_;
  half8 af[8];
#pragma unroll
  for (int ks = 0; ks < 8; ++ks) {
    const float4* p = reinterpret_cast<const float4*>(xrow + ks * 32 + kb * 8);
    float4 a = p[0], b = p[1];
    half8 v;
    v[0] = (f16)a.x; v[1] = (f16)a.y; v[2] = (f16)a.z; v[3] = (f16)a.w;
    v[4] = (f16)b.x; v[5] = (f16)b.y; v[6] = (f16)b.z; v[7] = (f16)b.w;
    af[ks] = v;
  }

#pragma unroll
  for (int ns = 0; ns < 4; ++ns) {
    const int nrow = n0 + ns * 16;
    const f16* wrow = wih + (size_t)(nrow + lr) * I_;
    floatx4 acc = {0.f, 0.f, 0.f, 0.f};
#pragma unroll
    for (int ks = 0; ks < 8; ++ks) {
      half8 bfr = *reinterpret_cast<const half8*>(wrow + ks * 32 + kb * 8);
      acc = __builtin_amdgcn_mfma_f32_16x16x32_f16(af[ks], bfr, acc, 0, 0, 0);
    }
    const int n = nrow + lr;
    const float bias = bih[n] + bhh[n];
#pragma unroll
    for (int r = 0; r < 4; ++r) {
      const int gm = m0 + (lane >> 4) * 4 + r;
      const int b = gm >> 9;
      const int t = gm & (T_ - 1);
      float v = acc[r] + bias;
      float po = __shfl_xor(v, 1);
      if (!(lane & 1)) {
        *reinterpret_cast<unsigned*>(xp + (size_t)(t * B_ + b) * H_ + n) =
            pack_f16x2(v, po);
      }
    }
  }
}

// ---------- recurrent kernel (flag-array sync, no atomics) ----------
// grid 256 x 256 thr. cluster c = wg&3 owns batches [c*16,+16);
// WG w = wg>>2 owns h rows [w*16,+16). W_hh stationary in VGPRs.
// Sync: WG stores flag[c][w]=s after its h[s] is at MALL; consumer wave wv
// polls only its 16 producers' flags (group line wv).
__global__ __launch_bounds__(256) void rnn3(
    const f16* __restrict__ whh,   // [H][H] f16
    const f16* __restrict__ xp,    // [T][B][H] f16 (biases folded in)
    f16* __restrict__ hbuf,        // [NCLUST][2][MB][H] f16
    int* __restrict__ flags) {     // [NCLUST][FSTRIDE]
  const int wg = blockIdx.x;
  const int c = wg & 3;
  const int w = wg >> 2;
  const int tid = threadIdx.x;
  const int wv = tid >> 6;
  const int lane = tid & 63;
  const int lr = lane & 15;
  const int kb = lane >> 4;
  const int n0 = w * ROWS;

  // stationary B-fragments: W_hh[n0+lr][wv*256 + i*32 + kb*8 ..+8]
  half8 bf[NMF];
#pragma unroll
  for (int i = 0; i < NMF; ++i) {
    const int k = wv * KPW + i * 32 + kb * 8;
    bf[i] = *reinterpret_cast<const half8*>(&whh[(size_t)(n0 + lr) * H_ + k]);
  }

  // this thread owns output (m, n0+nl)
  const int m = ((lane >> 4) << 2) | wv;
  const int nl = lane & 15;
  const f16* xq = xp + (size_t)(c * MB + m) * H_ + n0 + nl;

  __shared__ floatx4 red[4][64];
  f16* hc = hbuf + (size_t)c * 2 * MB * H_;
  int* fc = flags + c * FSTRIDE;
  int* myflag = fc + (w >> 4) * 32 + (w & 15);       // group line (w>>4), slot (w&15)
  const int* pollp = fc + wv * 32 + (lane & 15);     // wave wv's 16 producers

  for (int s = 1; s <= T_; ++s) {
    // prefetch this step's xp value (regular cached load; overlaps the poll)
    float xpv = (float)xq[(size_t)(s - 1) * (B_ * H_)];

    floatx4 acc0 = {0.f, 0.f, 0.f, 0.f}, acc1 = {0.f, 0.f, 0.f, 0.f};
    if (s > 1) {
      // wave-local poll: my 16 producers published h[s-1]
      int g = 0;
      for (;;) {
        int f = load_uc4(pollp);
        asm volatile("s_waitcnt vmcnt(0)" ::: "memory");
        if (__all(f >= s - 1)) break;
        if (++g > (1 << 12)) break;  // fail-fast valve (validation catches)
        __builtin_amdgcn_s_sleep(1);
      }
      __builtin_amdgcn_sched_barrier(0);

      const f16* hr = hc + (size_t)((s - 1) & 1) * MB * H_;
      uint4v af[NMF];
#pragma unroll
      for (int i = 0; i < NMF; ++i) {
        const int k = wv * KPW + i * 32 + kb * 8;
        af[i] = load_uc16(&hr[(size_t)lr * H_ + k]);
      }
      asm volatile("s_waitcnt vmcnt(0)" ::: "memory");
      __builtin_amdgcn_sched_barrier(0);
#pragma unroll
      for (int i = 0; i < NMF; ++i) {
        half8 a = __builtin_bit_cast(half8, af[i]);
        if (i & 1) acc1 = __builtin_amdgcn_mfma_f32_16x16x32_f16(a, bf[i], acc1, 0, 0, 0);
        else       acc0 = __builtin_amdgcn_mfma_f32_16x16x32_f16(a, bf[i], acc0, 0, 0, 0);
      }
    }

    red[wv][lane] = acc0 + acc1;
    __syncthreads();   // join waves: union of the 4 wave-polls = all 64 flags (WAR-safe)

    float v = red[0][lane][wv] + red[1][lane][wv] + red[2][lane][wv] +
              red[3][lane][wv] + xpv;
    float hn = tanhf(v);
    float po = __shfl_xor(hn, 1);
    f16* hw = hc + (size_t)(s & 1) * MB * H_;
    if (!(lane & 1)) {
      store_uc4(&hw[(size_t)m * H_ + n0 + nl], pack_f16x2(hn, po));
    }
    asm volatile("s_waitcnt vmcnt(0)" ::: "memory");  // this wave's h at MALL
    __syncthreads();                                   // all waves' h at MALL
    if (tid == 0) store_uc4(myflag, (unsigned)s);      // publish
  }
}

// ---------- FC head ----------
__global__ __launch_bounds__(256) void fc_head(
    const f16* __restrict__ hbuf, const f16* __restrict__ wfcT,
    const float* __restrict__ bfc, float* __restrict__ out) {
  __shared__ f16 hs[H_];
  const int b = blockIdx.x;
  const int c = b / MB, m = b % MB;
  const f16* hrow = hbuf + ((size_t)(c * 2) * MB + m) * H_;  // T_ even -> buffer 0
  const int o = threadIdx.x;
  reinterpret_cast<f16x4*>(hs)[o] = reinterpret_cast<const f16x4*>(hrow)[o];
  __syncthreads();
  float acc = bfc[o];
  const half8* wp = reinterpret_cast<const half8*>(wfcT) + o;
  const half8* hv = reinterpret_cast<const half8*>(hs);
#pragma unroll 8
  for (int c8 = 0; c8 < H_ / 8; ++c8) acc = dot8f(wp[(size_t)c8 * O_], hv[c8], acc);
  out[(size_t)b * O_ + o] = acc;
}

// ---------- round-1 fallback (weight-streaming, 3 MB ws) ----------
__global__ __launch_bounds__(1024) void rnn_f16(
    const float* __restrict__ x, const f16* __restrict__ wihT,
    const f16* __restrict__ whhT, const float* __restrict__ bih,
    const float* __restrict__ bhh, const f16* __restrict__ wfcT,
    const float* __restrict__ bfc, float* __restrict__ out) {
  __shared__ f16 hs[H_];
  __shared__ f16 xs[I_];
  const int b = blockIdx.x;
  const int j = threadIdx.x;
  const float bias = bih[j] + bhh[j];
  hs[j] = (f16)0.f;
  const half8* wih_p = reinterpret_cast<const half8*>(wihT) + j;
  const half8* whh_p = reinterpret_cast<const half8*>(whhT) + j;
  const half8* xv = reinterpret_cast<const half8*>(xs);
  const half8* hv = reinterpret_cast<const half8*>(hs);
  const float* xrow = x + (size_t)b * T_ * I_;
  for (int t = 0; t < T_; ++t) {
    if (j < I_) xs[j] = (f16)xrow[t * I_ + j];
    __syncthreads();
    float acc = bias;
#pragma unroll 8
    for (int c = 0; c < I_ / 8; ++c) acc = dot8f(wih_p[c * H_], xv[c], acc);
#pragma unroll 8
    for (int c = 0; c < H_ / 8; ++c) acc = dot8f(whh_p[c * H_], hv[c], acc);
    float hn = tanhf(acc);
    __syncthreads();
    hs[j] = (f16)hn;
  }
  __syncthreads();
  if (j < O_) {
    const half8* wfc_p = reinterpret_cast<const half8*>(wfcT) + j;
    float acc = bfc[j];
#pragma unroll 8
    for (int c = 0; c < H_ / 8; ++c) acc = dot8f(wfc_p[c * O_], hv[c], acc);
    out[(size_t)b * O_ + j] = acc;
  }
}

// ---------- fp32 fallback (0 ws) ----------
__global__ __launch_bounds__(1024) void rnn_fp32(
    const float* __restrict__ x,
    const float* __restrict__ Wih, const float* __restrict__ Whh,
    const float* __restrict__ bih, const float* __restrict__ bhh,
    const float* __restrict__ Wfc, const float* __restrict__ bfc,
    float* __restrict__ out) {
  __shared__ float hs[H_];
  __shared__ float xs[I_];
  const int b = blockIdx.x;
  const int j = threadIdx.x;
  const float bias = bih[j] + bhh[j];
  hs[j] = 0.f;
  const float4* wih_r = reinterpret_cast<const float4*>(Wih + (size_t)j * I_);
  const float4* whh_r = reinterpret_cast<const float4*>(Whh + (size_t)j * H_);
  const float4* xv = reinterpret_cast<const float4*>(xs);
  const float4* hv = reinterpret_cast<const float4*>(hs);
  const float* xrow = x + (size_t)b * T_ * I_;
  for (int t = 0; t < T_; ++t) {
    if (j < I_) xs[j] = xrow[t * I_ + j];
    __syncthreads();
    float acc = bias;
#pragma unroll 4
    for (int c = 0; c < I_ / 4; ++c) {
      float4 w = wih_r[c], v = xv[c];
      acc = fmaf(w.x, v.x, acc); acc = fmaf(w.y, v.y, acc);
      acc = fmaf(w.z, v.z, acc); acc = fmaf(w.w, v.w, acc);
    }
#pragma unroll 4
    for (int c = 0; c < H_ / 4; ++c) {
      float4 w = whh_r[c], v = hv[c];
      acc = fmaf(w.x, v.x, acc); acc = fmaf(w.y, v.y, acc);
      acc = fmaf(w.z, v.z, acc); acc = fmaf(w.w, v.w, acc);
    }
    float hn = tanhf(acc);
    __syncthreads();
    hs[j] = hn;
  }
  __syncthreads();
  if (j < O_) {
    float acc = bfc[j];
    const float4* wfc_r = reinterpret_cast<const float4*>(Wfc + (size_t)j * H_);
    for (int c = 0; c < H_ / 4; ++c) {
      float4 w = wfc_r[c], v = hv[c];
      acc = fmaf(w.x, v.x, acc); acc = fmaf(w.y, v.y, acc);
      acc = fmaf(w.z, v.z, acc); acc = fmaf(w.w, v.w, acc);
    }
    out[(size_t)b * O_ + j] = acc;
  }
}

extern "C" void kernel_launch(void* const* d_in, const int* in_sizes, int n_in,
                              void* d_out, int out_size, void* d_ws, size_t ws_size,
                              hipStream_t stream) {
  const float* x   = (const float*)d_in[0];
  const float* Wih = (const float*)d_in[1];
  const float* Whh = (const float*)d_in[2];
  const float* bih = (const float*)d_in[3];
  const float* bhh = (const float*)d_in[4];
  const float* Wfc = (const float*)d_in[5];
  const float* bfc = (const float*)d_in[6];
  float* out = (float*)d_out;

  const size_t n_whh = (size_t)H_ * H_;
  const size_t n_wih = (size_t)H_ * I_;
  const size_t n_wfc = (size_t)O_ * H_;
  const size_t n_xp  = (size_t)T_ * B_ * H_;
  const size_t n_h   = (size_t)NCLUST * 2 * MB * H_;

  size_t off = 0;
  const size_t o_whh = off; off += n_whh;
  const size_t o_wih = off; off += n_wih;
  const size_t o_wfc = off; off += n_wfc;
  const size_t o_xp  = off; off += n_xp;
  const size_t o_h   = off; off += n_h;
  size_t bytes_f16 = off * sizeof(f16);
  bytes_f16 = (bytes_f16 + 255) & ~(size_t)255;
  const size_t need_full = bytes_f16 + (size_t)NCLUST * FSTRIDE * sizeof(int);

  const int thr = 256;
  if (ws_size >= need_full) {
    f16* wsf   = (f16*)d_ws;
    f16* whh_h = wsf + o_whh;
    f16* wih_h = wsf + o_wih;
    f16* wfcT  = wsf + o_wfc;
    f16* xpb   = wsf + o_xp;
    f16* hbuf  = wsf + o_h;
    int* flags = (int*)((char*)d_ws + bytes_f16);

    init_flags<<<1, 256, 0, stream>>>(flags);
    cast_f16<<<(int)(n_whh / 4 / thr), thr, 0, stream>>>(Whh, whh_h, (int)(n_whh / 4));
    cast_f16<<<(int)(n_wih / 4 / thr), thr, 0, stream>>>(Wih, wih_h, (int)(n_wih / 4));
    convert_T8<<<(int)(n_wfc / 8 / thr), thr, 0, stream>>>(Wfc, wfcT, O_, H_);
    xp_gemm<<<(T_ * B_ / 64) * (H_ / 64), thr, 0, stream>>>(x, wih_h, bih, bhh, xpb);
    rnn3<<<NCLUST * WPC, thr, 0, stream>>>(whh_h, xpb, hbuf, flags);
    fc_head<<<B_, O_, 0, stream>>>(hbuf, wfcT, bfc, out);
  } else if (ws_size >= (n_wih + n_whh + n_wfc) * sizeof(f16)) {
    f16* wihT = (f16*)d_ws;
    f16* whhT = wihT + n_wih;
    f16* wfcT = whhT + n_whh;
    convert_T8<<<(int)((n_wih / 8 + thr - 1) / thr), thr, 0, stream>>>(Wih, wihT, H_, I_);
    convert_T8<<<(int)((n_whh / 8 + thr - 1) / thr), thr, 0, stream>>>(Whh, whhT, H_, H_);
    convert_T8<<<(int)((n_wfc / 8 + thr - 1) / thr), thr, 0, stream>>>(Wfc, wfcT, O_, H_);
    rnn_f16<<<B_, 1024, 0, stream>>>(x, wihT, whhT, bih, bhh, wfcT, bfc, out);
  } else {
    rnn_fp32<<<B_, 1024, 0, stream>>>(x, Wih, Whh, bih, bhh, Wfc, bfc, out);
  }
}

// Round 5
// 1758.766 us; speedup vs baseline: 12.5737x; 1.2239x over previous
//
#include <hip/hip_runtime.h>

#define B_ 64
#define T_ 512
#define I_ 256
#define H_ 1024
#define O_ 256

#define NCLUST 4
#define WPC 64        // workgroups per cluster
#define MB 16         // batches per cluster
#define ROWS 16       // h-rows per WG
#define NMF_H 8       // h-part MFMAs per wave (K=256)
#define NMF_X 2       // x-part MFMAs per wave (K=64)
#define KPW_H 256
#define KPW_X 64
#define FSTRIDE 256   // ints per cluster flag block

typedef _Float16 f16;
typedef _Float16 f16x2 __attribute__((ext_vector_type(2)));
typedef _Float16 f16x4 __attribute__((ext_vector_type(4)));
typedef _Float16 half8 __attribute__((ext_vector_type(8)));
typedef float floatx4 __attribute__((ext_vector_type(4)));
typedef unsigned int uint4v __attribute__((ext_vector_type(4)));

// ---------- memory helpers ----------
// bypass (coherence-point) ops: sc0 sc1 = skip L1+L2, hit MALL
__device__ __forceinline__ uint4v load_uc16(const void* p) {
  uint4v r;
  asm volatile("global_load_dwordx4 %0, %1, off sc0 sc1" : "=v"(r) : "v"(p));
  return r;
}
__device__ __forceinline__ int load_uc4(const void* p) {
  int r;
  asm volatile("global_load_dword %0, %1, off sc0 sc1" : "=v"(r) : "v"(p));
  return r;
}
__device__ __forceinline__ void store_uc4(void* p, unsigned v) {
  asm volatile("global_store_dword %0, %1, off sc0 sc1" :: "v"(p), "v"(v) : "memory");
}
// normal cached load, but as volatile asm so it can't be hoisted above the flag poll
__device__ __forceinline__ uint4v load_c16(const void* p) {
  uint4v r;
  asm volatile("global_load_dwordx4 %0, %1, off" : "=v"(r) : "v"(p));
  return r;
}
__device__ __forceinline__ unsigned pack_f16x2(float a, float b) {
  f16x2 t; t[0] = (f16)a; t[1] = (f16)b;
  return __builtin_bit_cast(unsigned, t);
}

#if __has_builtin(__builtin_amdgcn_fdot2)
__device__ __forceinline__ float dot2f(f16x2 a, f16x2 b, float c) {
  return __builtin_amdgcn_fdot2(a, b, c, false);
}
#else
__device__ __forceinline__ float dot2f(f16x2 a, f16x2 b, float c) {
  return fmaf((float)a[0], (float)b[0], fmaf((float)a[1], (float)b[1], c));
}
#endif

__device__ __forceinline__ float dot8f(half8 w, half8 v, float acc) {
  acc = dot2f(__builtin_shufflevector(w, w, 0, 1), __builtin_shufflevector(v, v, 0, 1), acc);
  acc = dot2f(__builtin_shufflevector(w, w, 2, 3), __builtin_shufflevector(v, v, 2, 3), acc);
  acc = dot2f(__builtin_shufflevector(w, w, 4, 5), __builtin_shufflevector(v, v, 4, 5), acc);
  acc = dot2f(__builtin_shufflevector(w, w, 6, 7), __builtin_shufflevector(v, v, 6, 7), acc);
  return acc;
}

// ---------- converters ----------
__global__ void cast_f16(const float* __restrict__ src, f16* __restrict__ dst, int n4) {
  int i = blockIdx.x * blockDim.x + threadIdx.x;
  if (i >= n4) return;
  float4 a = reinterpret_cast<const float4*>(src)[i];
  f16x4 v;
  v[0] = (f16)a.x; v[1] = (f16)a.y; v[2] = (f16)a.z; v[3] = (f16)a.w;
  reinterpret_cast<f16x4*>(dst)[i] = v;
}

__global__ void convert_T8(const float* __restrict__ src, f16* __restrict__ dst,
                           int R, int K) {
  int K8 = K >> 3;
  int total = R * K8;
  int idx = blockIdx.x * blockDim.x + threadIdx.x;
  if (idx >= total) return;
  int r = idx / K8;
  int k8 = idx - r * K8;
  const float4* s = reinterpret_cast<const float4*>(src + (size_t)r * K + (size_t)k8 * 8);
  float4 a = s[0], b = s[1];
  half8 v;
  v[0] = (f16)a.x; v[1] = (f16)a.y; v[2] = (f16)a.z; v[3] = (f16)a.w;
  v[4] = (f16)b.x; v[5] = (f16)b.y; v[6] = (f16)b.z; v[7] = (f16)b.w;
  reinterpret_cast<half8*>(dst)[(size_t)k8 * R + r] = v;
}

__global__ void init_flags(int* __restrict__ flags) {
  for (int i = threadIdx.x; i < NCLUST * FSTRIDE; i += blockDim.x) flags[i] = 0;
}

// ---------- tier-1 recurrent kernel ----------
// grid 256 x 256 thr. cluster c = wg&3 owns batches [c*16,+16);
// WG w = wg>>2 owns h rows [w*16,+16). W_hh, W_ih slices stationary in VGPRs.
// K=1280 split per wave: 256 h-cols + 64 x-cols.
// h[s] lives in hseq[s-1] (unique buffer per step -> cached reads are never stale).
// Producer: bypass-store h, vmcnt ack, barrier, bypass flag. Consumer: poll 16
// producer flags, then NORMAL cached loads (L2 fans out the 64x re-read).
__global__ __launch_bounds__(256) void rnn5(
    const f16* __restrict__ whh,   // [H][H] f16
    const f16* __restrict__ wih,   // [H][I] f16
    const f16* __restrict__ xbf,   // [B][T][I] f16
    const float* __restrict__ bih,
    const float* __restrict__ bhh,
    f16* __restrict__ hseq,        // [T][NCLUST][MB][H] f16
    int* __restrict__ flags) {     // [NCLUST][FSTRIDE]
  const int wg = blockIdx.x;
  const int c = wg & 3;
  const int w = wg >> 2;
  const int tid = threadIdx.x;
  const int wv = tid >> 6;
  const int lane = tid & 63;
  const int lr = lane & 15;
  const int kb = lane >> 4;
  const int n0 = w * ROWS;
  const int b0 = c * MB;

  // stationary B-fragments
  half8 bfh[NMF_H];
#pragma unroll
  for (int i = 0; i < NMF_H; ++i) {
    const int k = wv * KPW_H + i * 32 + kb * 8;
    bfh[i] = *reinterpret_cast<const half8*>(&whh[(size_t)(n0 + lr) * H_ + k]);
  }
  half8 bfx[NMF_X];
#pragma unroll
  for (int i = 0; i < NMF_X; ++i) {
    const int k = wv * KPW_X + i * 32 + kb * 8;
    bfx[i] = *reinterpret_cast<const half8*>(&wih[(size_t)(n0 + lr) * I_ + k]);
  }

  // this thread owns output (m, n0+nl) after the LDS reduce
  const int m = ((lane >> 4) << 2) | wv;
  const int nl = lane & 15;
  const float bias = bih[n0 + nl] + bhh[n0 + nl];

  // x A-operand: batch row b0+lr, step t cols [wv*64 + kb*8 ...]
  const f16* xrow = xbf + (size_t)(b0 + lr) * T_ * I_ + wv * KPW_X + kb * 8;

  __shared__ floatx4 red[4][64];
  int* fc = flags + c * FSTRIDE;
  int* myflag = fc + (w >> 4) * 32 + (w & 15);
  const int* pollp = fc + wv * 32 + lr;   // wave wv's 16 producers

  const size_t CST = (size_t)NCLUST * MB * H_;       // hseq per-step stride
  const size_t coff = (size_t)c * MB * H_;

  for (int s = 1; s <= T_; ++s) {
    // x loads issued before the poll: latency hides under the wait
    const f16* xs = xrow + (size_t)(s - 1) * I_;
    half8 ax0 = *reinterpret_cast<const half8*>(xs);
    half8 ax1 = *reinterpret_cast<const half8*>(xs + 32);

    uint4v af[NMF_H];
    if (s > 1) {
      int g = 0;
      for (;;) {
        int f = load_uc4(pollp);
        asm volatile("s_waitcnt vmcnt(0)" ::: "memory");
        if (__all(f >= s - 1)) break;
        if (++g > (1 << 12)) break;  // fail-fast valve (validation catches)
        __builtin_amdgcn_s_sleep(1);
      }
      const f16* hr = hseq + (size_t)(s - 2) * CST + coff;  // h[s-1]
#pragma unroll
      for (int i = 0; i < NMF_H; ++i) {
        const int k = wv * KPW_H + i * 32 + kb * 8;
        af[i] = load_c16(&hr[(size_t)lr * H_ + k]);
      }
      asm volatile("s_waitcnt vmcnt(0)" ::: "memory");
      __builtin_amdgcn_sched_barrier(0);
    }

    floatx4 acc0 = {0.f, 0.f, 0.f, 0.f}, acc1 = {0.f, 0.f, 0.f, 0.f};
    acc0 = __builtin_amdgcn_mfma_f32_16x16x32_f16(ax0, bfx[0], acc0, 0, 0, 0);
    acc1 = __builtin_amdgcn_mfma_f32_16x16x32_f16(ax1, bfx[1], acc1, 0, 0, 0);
    if (s > 1) {
#pragma unroll
      for (int i = 0; i < NMF_H; ++i) {
        half8 a = __builtin_bit_cast(half8, af[i]);
        if (i & 1) acc1 = __builtin_amdgcn_mfma_f32_16x16x32_f16(a, bfh[i], acc1, 0, 0, 0);
        else       acc0 = __builtin_amdgcn_mfma_f32_16x16x32_f16(a, bfh[i], acc0, 0, 0, 0);
      }
    }

    red[wv][lane] = acc0 + acc1;
    __syncthreads();

    float v = red[0][lane][wv] + red[1][lane][wv] + red[2][lane][wv] +
              red[3][lane][wv] + bias;
    float hn = tanhf(v);
    float po = __shfl_xor(hn, 1);
    f16* hw = hseq + (size_t)(s - 1) * CST + coff;
    if (!(lane & 1)) {
      store_uc4(&hw[(size_t)m * H_ + n0 + nl], pack_f16x2(hn, po));
    }
    asm volatile("s_waitcnt vmcnt(0)" ::: "memory");  // h at MALL
    __syncthreads();                                   // all 4 waves drained
    if (tid == 0) store_uc4(myflag, (unsigned)s);      // publish
  }
}

// FC head over flat h_last rows: row b at hlast + b*H_
__global__ __launch_bounds__(256) void fc_head_flat(
    const f16* __restrict__ hlast, const f16* __restrict__ wfcT,
    const float* __restrict__ bfc, float* __restrict__ out) {
  __shared__ f16 hs[H_];
  const int b = blockIdx.x;
  const int o = threadIdx.x;
  reinterpret_cast<f16x4*>(hs)[o] =
      reinterpret_cast<const f16x4*>(hlast + (size_t)b * H_)[o];
  __syncthreads();
  float acc = bfc[o];
  const half8* wp = reinterpret_cast<const half8*>(wfcT) + o;
  const half8* hv = reinterpret_cast<const half8*>(hs);
#pragma unroll 8
  for (int c8 = 0; c8 < H_ / 8; ++c8) acc = dot8f(wp[(size_t)c8 * O_], hv[c8], acc);
  out[(size_t)b * O_ + o] = acc;
}

// ================= tier-2: round-4 validated path =================
__global__ __launch_bounds__(256) void xp_gemm(
    const float* __restrict__ x, const f16* __restrict__ wih,
    const float* __restrict__ bih, const float* __restrict__ bhh,
    f16* __restrict__ xp) {
  const int wg = blockIdx.x;
  const int mt = wg >> 4;
  const int nt = wg & 15;
  const int wv = threadIdx.x >> 6;
  const int lane = threadIdx.x & 63;
  const int lr = lane & 15;
  const int kb = lane >> 4;
  const int m0 = mt * 64 + wv * 16;
  const int n0 = nt * 64;

  const float* xrow = x + (size_t)(m0 + lr) * I_;
  half8 af[8];
#pragma unroll
  for (int ks = 0; ks < 8; ++ks) {
    const float4* p = reinterpret_cast<const float4*>(xrow + ks * 32 + kb * 8);
    float4 a = p[0], b = p[1];
    half8 v;
    v[0] = (f16)a.x; v[1] = (f16)a.y; v[2] = (f16)a.z; v[3] = (f16)a.w;
    v[4] = (f16)b.x; v[5] = (f16)b.y; v[6] = (f16)b.z; v[7] = (f16)b.w;
    af[ks] = v;
  }
#pragma unroll
  for (int ns = 0; ns < 4; ++ns) {
    const int nrow = n0 + ns * 16;
    const f16* wrow = wih + (size_t)(nrow + lr) * I_;
    floatx4 acc = {0.f, 0.f, 0.f, 0.f};
#pragma unroll
    for (int ks = 0; ks < 8; ++ks) {
      half8 bfr = *reinterpret_cast<const half8*>(wrow + ks * 32 + kb * 8);
      acc = __builtin_amdgcn_mfma_f32_16x16x32_f16(af[ks], bfr, acc, 0, 0, 0);
    }
    const int n = nrow + lr;
    const float bias = bih[n] + bhh[n];
#pragma unroll
    for (int r = 0; r < 4; ++r) {
      const int gm = m0 + (lane >> 4) * 4 + r;
      const int b = gm >> 9;
      const int t = gm & (T_ - 1);
      float v = acc[r] + bias;
      float po = __shfl_xor(v, 1);
      if (!(lane & 1)) {
        *reinterpret_cast<unsigned*>(xp + (size_t)(t * B_ + b) * H_ + n) =
            pack_f16x2(v, po);
      }
    }
  }
}

__global__ __launch_bounds__(256) void rnn3(
    const f16* __restrict__ whh, const f16* __restrict__ xp,
    f16* __restrict__ hbuf, int* __restrict__ flags) {
  const int wg = blockIdx.x;
  const int c = wg & 3;
  const int w = wg >> 2;
  const int tid = threadIdx.x;
  const int wv = tid >> 6;
  const int lane = tid & 63;
  const int lr = lane & 15;
  const int kb = lane >> 4;
  const int n0 = w * ROWS;

  half8 bf[NMF_H];
#pragma unroll
  for (int i = 0; i < NMF_H; ++i) {
    const int k = wv * KPW_H + i * 32 + kb * 8;
    bf[i] = *reinterpret_cast<const half8*>(&whh[(size_t)(n0 + lr) * H_ + k]);
  }
  const int m = ((lane >> 4) << 2) | wv;
  const int nl = lane & 15;
  const f16* xq = xp + (size_t)(c * MB + m) * H_ + n0 + nl;

  __shared__ floatx4 red[4][64];
  f16* hc = hbuf + (size_t)c * 2 * MB * H_;
  int* fc = flags + c * FSTRIDE;
  int* myflag = fc + (w >> 4) * 32 + (w & 15);
  const int* pollp = fc + wv * 32 + (lane & 15);

  for (int s = 1; s <= T_; ++s) {
    float xpv = (float)xq[(size_t)(s - 1) * (B_ * H_)];
    floatx4 acc0 = {0.f, 0.f, 0.f, 0.f}, acc1 = {0.f, 0.f, 0.f, 0.f};
    if (s > 1) {
      int g = 0;
      for (;;) {
        int f = load_uc4(pollp);
        asm volatile("s_waitcnt vmcnt(0)" ::: "memory");
        if (__all(f >= s - 1)) break;
        if (++g > (1 << 12)) break;
        __builtin_amdgcn_s_sleep(1);
      }
      __builtin_amdgcn_sched_barrier(0);
      const f16* hr = hc + (size_t)((s - 1) & 1) * MB * H_;
      uint4v af[NMF_H];
#pragma unroll
      for (int i = 0; i < NMF_H; ++i) {
        const int k = wv * KPW_H + i * 32 + kb * 8;
        af[i] = load_uc16(&hr[(size_t)lr * H_ + k]);
      }
      asm volatile("s_waitcnt vmcnt(0)" ::: "memory");
      __builtin_amdgcn_sched_barrier(0);
#pragma unroll
      for (int i = 0; i < NMF_H; ++i) {
        half8 a = __builtin_bit_cast(half8, af[i]);
        if (i & 1) acc1 = __builtin_amdgcn_mfma_f32_16x16x32_f16(a, bf[i], acc1, 0, 0, 0);
        else       acc0 = __builtin_amdgcn_mfma_f32_16x16x32_f16(a, bf[i], acc0, 0, 0, 0);
      }
    }
    red[wv][lane] = acc0 + acc1;
    __syncthreads();
    float v = red[0][lane][wv] + red[1][lane][wv] + red[2][lane][wv] +
              red[3][lane][wv] + xpv;
    float hn = tanhf(v);
    float po = __shfl_xor(hn, 1);
    f16* hw = hc + (size_t)(s & 1) * MB * H_;
    if (!(lane & 1)) {
      store_uc4(&hw[(size_t)m * H_ + n0 + nl], pack_f16x2(hn, po));
    }
    asm volatile("s_waitcnt vmcnt(0)" ::: "memory");
    __syncthreads();
    if (tid == 0) store_uc4(myflag, (unsigned)s);
  }
}

__global__ __launch_bounds__(256) void fc_head(
    const f16* __restrict__ hbuf, const f16* __restrict__ wfcT,
    const float* __restrict__ bfc, float* __restrict__ out) {
  __shared__ f16 hs[H_];
  const int b = blockIdx.x;
  const int c = b / MB, m = b % MB;
  const f16* hrow = hbuf + ((size_t)(c * 2) * MB + m) * H_;
  const int o = threadIdx.x;
  reinterpret_cast<f16x4*>(hs)[o] = reinterpret_cast<const f16x4*>(hrow)[o];
  __syncthreads();
  float acc = bfc[o];
  const half8* wp = reinterpret_cast<const half8*>(wfcT) + o;
  const half8* hv = reinterpret_cast<const half8*>(hs);
#pragma unroll 8
  for (int c8 = 0; c8 < H_ / 8; ++c8) acc = dot8f(wp[(size_t)c8 * O_], hv[c8], acc);
  out[(size_t)b * O_ + o] = acc;
}

// ---------- tier-3: round-1 weight-streaming ----------
__global__ __launch_bounds__(1024) void rnn_f16(
    const float* __restrict__ x, const f16* __restrict__ wihT,
    const f16* __restrict__ whhT, const float* __restrict__ bih,
    const float* __restrict__ bhh, const f16* __restrict__ wfcT,
    const float* __restrict__ bfc, float* __restrict__ out) {
  __shared__ f16 hs[H_];
  __shared__ f16 xs[I_];
  const int b = blockIdx.x;
  const int j = threadIdx.x;
  const float bias = bih[j] + bhh[j];
  hs[j] = (f16)0.f;
  const half8* wih_p = reinterpret_cast<const half8*>(wihT) + j;
  const half8* whh_p = reinterpret_cast<const half8*>(whhT) + j;
  const half8* xv = reinterpret_cast<const half8*>(xs);
  const half8* hv = reinterpret_cast<const half8*>(hs);
  const float* xrow = x + (size_t)b * T_ * I_;
  for (int t = 0; t < T_; ++t) {
    if (j < I_) xs[j] = (f16)xrow[t * I_ + j];
    __syncthreads();
    float acc = bias;
#pragma unroll 8
    for (int c = 0; c < I_ / 8; ++c) acc = dot8f(wih_p[c * H_], xv[c], acc);
#pragma unroll 8
    for (int c = 0; c < H_ / 8; ++c) acc = dot8f(whh_p[c * H_], hv[c], acc);
    float hn = tanhf(acc);
    __syncthreads();
    hs[j] = (f16)hn;
  }
  __syncthreads();
  if (j < O_) {
    const half8* wfc_p = reinterpret_cast<const half8*>(wfcT) + j;
    float acc = bfc[j];
#pragma unroll 8
    for (int c = 0; c < H_ / 8; ++c) acc = dot8f(wfc_p[c * O_], hv[c], acc);
    out[(size_t)b * O_ + j] = acc;
  }
}

// ---------- tier-4: fp32, zero ws ----------
__global__ __launch_bounds__(1024) void rnn_fp32(
    const float* __restrict__ x,
    const float* __restrict__ Wih, const float* __restrict__ Whh,
    const float* __restrict__ bih, const float* __restrict__ bhh,
    const float* __restrict__ Wfc, const float* __restrict__ bfc,
    float* __restrict__ out) {
  __shared__ float hs[H_];
  __shared__ float xs[I_];
  const int b = blockIdx.x;
  const int j = threadIdx.x;
  const float bias = bih[j] + bhh[j];
  hs[j] = 0.f;
  const float4* wih_r = reinterpret_cast<const float4*>(Wih + (size_t)j * I_);
  const float4* whh_r = reinterpret_cast<const float4*>(Whh + (size_t)j * H_);
  const float4* xv = reinterpret_cast<const float4*>(xs);
  const float4* hv = reinterpret_cast<const float4*>(hs);
  const float* xrow = x + (size_t)b * T_ * I_;
  for (int t = 0; t < T_; ++t) {
    if (j < I_) xs[j] = xrow[t * I_ + j];
    __syncthreads();
    float acc = bias;
#pragma unroll 4
    for (int c = 0; c < I_ / 4; ++c) {
      float4 w = wih_r[c], v = xv[c];
      acc = fmaf(w.x, v.x, acc); acc = fmaf(w.y, v.y, acc);
      acc = fmaf(w.z, v.z, acc); acc = fmaf(w.w, v.w, acc);
    }
#pragma unroll 4
    for (int c = 0; c < H_ / 4; ++c) {
      float4 w = whh_r[c], v = hv[c];
      acc = fmaf(w.x, v.x, acc); acc = fmaf(w.y, v.y, acc);
      acc = fmaf(w.z, v.z, acc); acc = fmaf(w.w, v.w, acc);
    }
    float hn = tanhf(acc);
    __syncthreads();
    hs[j] = hn;
  }
  __syncthreads();
  if (j < O_) {
    float acc = bfc[j];
    const float4* wfc_r = reinterpret_cast<const float4*>(Wfc + (size_t)j * H_);
    for (int c = 0; c < H_ / 4; ++c) {
      float4 w = wfc_r[c], v = hv[c];
      acc = fmaf(w.x, v.x, acc); acc = fmaf(w.y, v.y, acc);
      acc = fmaf(w.z, v.z, acc); acc = fmaf(w.w, v.w, acc);
    }
    out[(size_t)b * O_ + j] = acc;
  }
}

extern "C" void kernel_launch(void* const* d_in, const int* in_sizes, int n_in,
                              void* d_out, int out_size, void* d_ws, size_t ws_size,
                              hipStream_t stream) {
  const float* x   = (const float*)d_in[0];
  const float* Wih = (const float*)d_in[1];
  const float* Whh = (const float*)d_in[2];
  const float* bih = (const float*)d_in[3];
  const float* bhh = (const float*)d_in[4];
  const float* Wfc = (const float*)d_in[5];
  const float* bfc = (const float*)d_in[6];
  float* out = (float*)d_out;

  const size_t n_whh = (size_t)H_ * H_;
  const size_t n_wih = (size_t)H_ * I_;
  const size_t n_wfc = (size_t)O_ * H_;
  const size_t n_x   = (size_t)B_ * T_ * I_;
  const size_t n_xp  = (size_t)T_ * B_ * H_;
  const size_t n_hseq = (size_t)T_ * NCLUST * MB * H_;
  const size_t n_h2  = (size_t)NCLUST * 2 * MB * H_;
  const int thr = 256;

  // ---- tier 1 layout: whh | wih | wfcT | xbf | hseq | flags  (~87 MB)
  {
    size_t off = 0;
    const size_t o_whh = off; off += n_whh;
    const size_t o_wih = off; off += n_wih;
    const size_t o_wfc = off; off += n_wfc;
    const size_t o_x   = off; off += n_x;
    const size_t o_hs  = off; off += n_hseq;
    size_t bytes_f16 = off * sizeof(f16);
    bytes_f16 = (bytes_f16 + 255) & ~(size_t)255;
    const size_t need1 = bytes_f16 + (size_t)NCLUST * FSTRIDE * sizeof(int);

    if (ws_size >= need1) {
      f16* wsf   = (f16*)d_ws;
      f16* whh_h = wsf + o_whh;
      f16* wih_h = wsf + o_wih;
      f16* wfcT  = wsf + o_wfc;
      f16* xbf   = wsf + o_x;
      f16* hseq  = wsf + o_hs;
      int* flags = (int*)((char*)d_ws + bytes_f16);

      init_flags<<<1, 256, 0, stream>>>(flags);
      cast_f16<<<(int)(n_whh / 4 / thr), thr, 0, stream>>>(Whh, whh_h, (int)(n_whh / 4));
      cast_f16<<<(int)(n_wih / 4 / thr), thr, 0, stream>>>(Wih, wih_h, (int)(n_wih / 4));
      cast_f16<<<(int)(n_x / 4 / thr), thr, 0, stream>>>(x, xbf, (int)(n_x / 4));
      convert_T8<<<(int)(n_wfc / 8 / thr), thr, 0, stream>>>(Wfc, wfcT, O_, H_);
      rnn5<<<NCLUST * WPC, thr, 0, stream>>>(whh_h, wih_h, xbf, bih, bhh, hseq, flags);
      const f16* hlast = hseq + (size_t)(T_ - 1) * NCLUST * MB * H_;
      fc_head_flat<<<B_, O_, 0, stream>>>(hlast, wfcT, bfc, out);
      return;
    }
  }

  // ---- tier 2 layout (round-4): whh | wih | wfcT | xp | hbuf | flags (~73 MB)
  {
    size_t off = 0;
    const size_t o_whh = off; off += n_whh;
    const size_t o_wih = off; off += n_wih;
    const size_t o_wfc = off; off += n_wfc;
    const size_t o_xp  = off; off += n_xp;
    const size_t o_h   = off; off += n_h2;
    size_t bytes_f16 = off * sizeof(f16);
    bytes_f16 = (bytes_f16 + 255) & ~(size_t)255;
    const size_t need2 = bytes_f16 + (size_t)NCLUST * FSTRIDE * sizeof(int);

    if (ws_size >= need2) {
      f16* wsf   = (f16*)d_ws;
      f16* whh_h = wsf + o_whh;
      f16* wih_h = wsf + o_wih;
      f16* wfcT  = wsf + o_wfc;
      f16* xpb   = wsf + o_xp;
      f16* hbuf  = wsf + o_h;
      int* flags = (int*)((char*)d_ws + bytes_f16);

      init_flags<<<1, 256, 0, stream>>>(flags);
      cast_f16<<<(int)(n_whh / 4 / thr), thr, 0, stream>>>(Whh, whh_h, (int)(n_whh / 4));
      cast_f16<<<(int)(n_wih / 4 / thr), thr, 0, stream>>>(Wih, wih_h, (int)(n_wih / 4));
      convert_T8<<<(int)(n_wfc / 8 / thr), thr, 0, stream>>>(Wfc, wfcT, O_, H_);
      xp_gemm<<<(T_ * B_ / 64) * (H_ / 64), thr, 0, stream>>>(x, wih_h, bih, bhh, xpb);
      rnn3<<<NCLUST * WPC, thr, 0, stream>>>(whh_h, xpb, hbuf, flags);
      fc_head<<<B_, O_, 0, stream>>>(hbuf, wfcT, bfc, out);
      return;
    }
  }

  // ---- tier 3 (3 MB) / tier 4 (0)
  if (ws_size >= (n_wih + n_whh + n_wfc) * sizeof(f16)) {
    f16* wihT = (f16*)d_ws;
    f16* whhT = wihT + n_wih;
    f16* wfcT = whhT + n_whh;
    convert_T8<<<(int)((n_wih / 8 + thr - 1) / thr), thr, 0, stream>>>(Wih, wihT, H_, I_);
    convert_T8<<<(int)((n_whh / 8 + thr - 1) / thr), thr, 0, stream>>>(Whh, whhT, H_, H_);
    convert_T8<<<(int)((n_wfc / 8 + thr - 1) / thr), thr, 0, stream>>>(Wfc, wfcT, O_, H_);
    rnn_f16<<<B_, 1024, 0, stream>>>(x, wihT, whhT, bih, bhh, wfcT, bfc, out);
  } else {
    rnn_fp32<<<B_, 1024, 0, stream>>>(x, Wih, Whh, bih, bhh, Wfc, bfc, out);
  }
}

// Round 6
// 1170.010 us; speedup vs baseline: 18.9009x; 1.5032x over previous
//
#include <hip/hip_runtime.h>

#define B_ 64
#define T_ 512
#define I_ 256
#define H_ 1024
#define O_ 256

#define NCLUST 4
#define WPC 64        // workgroups per cluster
#define MB 16         // batches per cluster
#define ROWS 16       // h-rows per WG
#define NMF_H 8       // h-part MFMAs per wave (K=256)
#define NMF_X 2       // x-part MFMAs per wave (K=64)
#define KPW_H 256
#define KPW_X 64
#define SENT 0x7FFF7FFFu   // f16 NaN pair: tanh output can never equal this

typedef _Float16 f16;
typedef _Float16 f16x2 __attribute__((ext_vector_type(2)));
typedef _Float16 f16x4 __attribute__((ext_vector_type(4)));
typedef _Float16 half8 __attribute__((ext_vector_type(8)));
typedef float floatx4 __attribute__((ext_vector_type(4)));
typedef unsigned int uint4v __attribute__((ext_vector_type(4)));

// ---------- memory helpers ----------
// bypass (coherence-point) ops: sc0 sc1 = skip L1+L2, access MALL directly
__device__ __forceinline__ uint4v load_uc16(const void* p) {
  uint4v r;
  asm volatile("global_load_dwordx4 %0, %1, off sc0 sc1" : "=v"(r) : "v"(p));
  return r;
}
__device__ __forceinline__ void store_uc4(void* p, unsigned v) {
  asm volatile("global_store_dword %0, %1, off sc0 sc1" :: "v"(p), "v"(v) : "memory");
}
__device__ __forceinline__ void store_uc16(void* p, uint4v v) {
  asm volatile("global_store_dwordx4 %0, %1, off sc0 sc1" :: "v"(p), "v"(v) : "memory");
}
__device__ __forceinline__ unsigned pack_f16x2(float a, float b) {
  f16x2 t; t[0] = (f16)a; t[1] = (f16)b;
  return __builtin_bit_cast(unsigned, t);
}

#if __has_builtin(__builtin_amdgcn_fdot2)
__device__ __forceinline__ float dot2f(f16x2 a, f16x2 b, float c) {
  return __builtin_amdgcn_fdot2(a, b, c, false);
}
#else
__device__ __forceinline__ float dot2f(f16x2 a, f16x2 b, float c) {
  return fmaf((float)a[0], (float)b[0], fmaf((float)a[1], (float)b[1], c));
}
#endif

__device__ __forceinline__ float dot8f(half8 w, half8 v, float acc) {
  acc = dot2f(__builtin_shufflevector(w, w, 0, 1), __builtin_shufflevector(v, v, 0, 1), acc);
  acc = dot2f(__builtin_shufflevector(w, w, 2, 3), __builtin_shufflevector(v, v, 2, 3), acc);
  acc = dot2f(__builtin_shufflevector(w, w, 4, 5), __builtin_shufflevector(v, v, 4, 5), acc);
  acc = dot2f(__builtin_shufflevector(w, w, 6, 7), __builtin_shufflevector(v, v, 6, 7), acc);
  return acc;
}

// ---------- converters / init ----------
__global__ void cast_f16(const float* __restrict__ src, f16* __restrict__ dst, int n4) {
  int i = blockIdx.x * blockDim.x + threadIdx.x;
  if (i >= n4) return;
  float4 a = reinterpret_cast<const float4*>(src)[i];
  f16x4 v;
  v[0] = (f16)a.x; v[1] = (f16)a.y; v[2] = (f16)a.z; v[3] = (f16)a.w;
  reinterpret_cast<f16x4*>(dst)[i] = v;
}

__global__ void convert_T8(const float* __restrict__ src, f16* __restrict__ dst,
                           int R, int K) {
  int K8 = K >> 3;
  int total = R * K8;
  int idx = blockIdx.x * blockDim.x + threadIdx.x;
  if (idx >= total) return;
  int r = idx / K8;
  int k8 = idx - r * K8;
  const float4* s = reinterpret_cast<const float4*>(src + (size_t)r * K + (size_t)k8 * 8);
  float4 a = s[0], b = s[1];
  half8 v;
  v[0] = (f16)a.x; v[1] = (f16)a.y; v[2] = (f16)a.z; v[3] = (f16)a.w;
  v[4] = (f16)b.x; v[5] = (f16)b.y; v[6] = (f16)b.z; v[7] = (f16)b.w;
  reinterpret_cast<half8*>(dst)[(size_t)k8 * R + r] = v;
}

// sentinel-fill hseq via bypass stores (must be at MALL, not dirty in some L2,
// so that consumers' bypass reads see it). Re-run every launch: replay-safe.
__global__ void init_hseq(unsigned* __restrict__ p, long n16) {
  uint4v sv; sv[0] = SENT; sv[1] = SENT; sv[2] = SENT; sv[3] = SENT;
  long i = (long)blockIdx.x * blockDim.x + threadIdx.x;
  const long stride = (long)gridDim.x * blockDim.x;
  for (; i < n16; i += stride) store_uc16(p + 4 * i, sv);
}

// ---------- tier-1 recurrent kernel: sentinel dataflow ----------
// grid 256 x 256 thr. cluster c = wg&3 owns batches [c*16,+16);
// WG w = wg>>2 owns h rows [w*16,+16). W_hh/W_ih slices stationary in VGPRs.
// h[s] lives in hseq[s-1] (unique per step; sentinel-initialized).
// Producer: bypass-store h pairs, fire-and-forget (data IS the flag).
// Consumer: bypass-load its 8 packets and retry until no dword == SENT;
// on success the operands are already in registers. No acks/flags/atomics.
__global__ __launch_bounds__(256) void rnn6(
    const f16* __restrict__ whh,   // [H][H] f16
    const f16* __restrict__ wih,   // [H][I] f16
    const f16* __restrict__ xbf,   // [B][T][I] f16
    const float* __restrict__ bih,
    const float* __restrict__ bhh,
    f16* __restrict__ hseq) {      // [T][NCLUST][MB][H] f16 (sentinel-filled)
  const int wg = blockIdx.x;
  const int c = wg & 3;
  const int w = wg >> 2;
  const int tid = threadIdx.x;
  const int wv = tid >> 6;
  const int lane = tid & 63;
  const int lr = lane & 15;
  const int kb = lane >> 4;
  const int n0 = w * ROWS;
  const int b0 = c * MB;

  // stationary B-fragments
  half8 bfh[NMF_H];
#pragma unroll
  for (int i = 0; i < NMF_H; ++i) {
    const int k = wv * KPW_H + i * 32 + kb * 8;
    bfh[i] = *reinterpret_cast<const half8*>(&whh[(size_t)(n0 + lr) * H_ + k]);
  }
  half8 bfx[NMF_X];
#pragma unroll
  for (int i = 0; i < NMF_X; ++i) {
    const int k = wv * KPW_X + i * 32 + kb * 8;
    bfx[i] = *reinterpret_cast<const half8*>(&wih[(size_t)(n0 + lr) * I_ + k]);
  }

  // output ownership after reduce (validated mapping)
  const int m = ((lane >> 4) << 2) | wv;
  const int nl = lane & 15;
  const float bias = bih[n0 + nl] + bhh[n0 + nl];

  // x A-operand: batch row b0+lr, step t cols [wv*64 + kb*8 ...]
  const f16* xrow = xbf + (size_t)(b0 + lr) * T_ * I_ + wv * KPW_X + kb * 8;

  __shared__ floatx4 red[2][4][64];   // parity double-buffer -> 1 barrier/step
  const size_t CST = (size_t)NCLUST * MB * H_;
  const size_t coff = (size_t)c * MB * H_;

  for (int s = 1; s <= T_; ++s) {
    // x loads (cached) issued before the poll: latency hides under the wait
    const f16* xs = xrow + (size_t)(s - 1) * I_;
    half8 ax0 = *reinterpret_cast<const half8*>(xs);
    half8 ax1 = *reinterpret_cast<const half8*>(xs + 32);

    floatx4 acc0 = {0.f, 0.f, 0.f, 0.f}, acc1 = {0.f, 0.f, 0.f, 0.f};
    acc0 = __builtin_amdgcn_mfma_f32_16x16x32_f16(ax0, bfx[0], acc0, 0, 0, 0);
    acc1 = __builtin_amdgcn_mfma_f32_16x16x32_f16(ax1, bfx[1], acc1, 0, 0, 0);

    if (s > 1) {
      const f16* hr = hseq + (size_t)(s - 2) * CST + coff;  // h[s-1]
      uint4v af[NMF_H];
      int g = 0;
      for (;;) {
        // merged poll+load: fetch all 8 packets from MALL
#pragma unroll
        for (int i = 0; i < NMF_H; ++i) {
          const int k = wv * KPW_H + i * 32 + kb * 8;
          af[i] = load_uc16(&hr[(size_t)lr * H_ + k]);
        }
        asm volatile("s_waitcnt vmcnt(0)" ::: "memory");
        unsigned bad = 0u;
#pragma unroll
        for (int i = 0; i < NMF_H; ++i) {
          bad |= (unsigned)(af[i][0] == SENT);
          bad |= (unsigned)(af[i][1] == SENT);
          bad |= (unsigned)(af[i][2] == SENT);
          bad |= (unsigned)(af[i][3] == SENT);
        }
        if (__all(bad == 0u)) break;            // all dwords written -> data valid
        if (++g > (1 << 14)) break;             // fail-fast valve (no hang)
        __builtin_amdgcn_s_sleep(1);
      }
      __builtin_amdgcn_sched_barrier(0);
#pragma unroll
      for (int i = 0; i < NMF_H; ++i) {
        half8 a = __builtin_bit_cast(half8, af[i]);
        if (i & 1) acc1 = __builtin_amdgcn_mfma_f32_16x16x32_f16(a, bfh[i], acc1, 0, 0, 0);
        else       acc0 = __builtin_amdgcn_mfma_f32_16x16x32_f16(a, bfh[i], acc0, 0, 0, 0);
      }
    }

    // K-split reduce (parity-buffered: single barrier per step)
    const int pr = s & 1;
    red[pr][wv][lane] = acc0 + acc1;
    __syncthreads();

    float v = red[pr][0][lane][wv] + red[pr][1][lane][wv] +
              red[pr][2][lane][wv] + red[pr][3][lane][wv] + bias;
    float hn = tanhf(v);
    float po = __shfl_xor(hn, 1);
    f16* hw = hseq + (size_t)(s - 1) * CST + coff;
    if (!(lane & 1)) {
      store_uc4(&hw[(size_t)m * H_ + n0 + nl], pack_f16x2(hn, po));
    }
    // fire-and-forget: no ack, no flag, no trailing barrier.
  }
}

// FC head over flat h_last rows: row b at hlast + b*H_
__global__ __launch_bounds__(256) void fc_head_flat(
    const f16* __restrict__ hlast, const f16* __restrict__ wfcT,
    const float* __restrict__ bfc, float* __restrict__ out) {
  __shared__ f16 hs[H_];
  const int b = blockIdx.x;
  const int o = threadIdx.x;
  reinterpret_cast<f16x4*>(hs)[o] =
      reinterpret_cast<const f16x4*>(hlast + (size_t)b * H_)[o];
  __syncthreads();
  float acc = bfc[o];
  const half8* wp = reinterpret_cast<const half8*>(wfcT) + o;
  const half8* hv = reinterpret_cast<const half8*>(hs);
#pragma unroll 8
  for (int c8 = 0; c8 < H_ / 8; ++c8) acc = dot8f(wp[(size_t)c8 * O_], hv[c8], acc);
  out[(size_t)b * O_ + o] = acc;
}

// ---------- tier-3: round-1 weight-streaming (3 MB ws) ----------
__global__ __launch_bounds__(1024) void rnn_f16(
    const float* __restrict__ x, const f16* __restrict__ wihT,
    const f16* __restrict__ whhT, const float* __restrict__ bih,
    const float* __restrict__ bhh, const f16* __restrict__ wfcT,
    const float* __restrict__ bfc, float* __restrict__ out) {
  __shared__ f16 hs[H_];
  __shared__ f16 xs[I_];
  const int b = blockIdx.x;
  const int j = threadIdx.x;
  const float bias = bih[j] + bhh[j];
  hs[j] = (f16)0.f;
  const half8* wih_p = reinterpret_cast<const half8*>(wihT) + j;
  const half8* whh_p = reinterpret_cast<const half8*>(whhT) + j;
  const half8* xv = reinterpret_cast<const half8*>(xs);
  const half8* hv = reinterpret_cast<const half8*>(hs);
  const float* xrow = x + (size_t)b * T_ * I_;
  for (int t = 0; t < T_; ++t) {
    if (j < I_) xs[j] = (f16)xrow[t * I_ + j];
    __syncthreads();
    float acc = bias;
#pragma unroll 8
    for (int c = 0; c < I_ / 8; ++c) acc = dot8f(wih_p[c * H_], xv[c], acc);
#pragma unroll 8
    for (int c = 0; c < H_ / 8; ++c) acc = dot8f(whh_p[c * H_], hv[c], acc);
    float hn = tanhf(acc);
    __syncthreads();
    hs[j] = (f16)hn;
  }
  __syncthreads();
  if (j < O_) {
    const half8* wfc_p = reinterpret_cast<const half8*>(wfcT) + j;
    float acc = bfc[j];
#pragma unroll 8
    for (int c = 0; c < H_ / 8; ++c) acc = dot8f(wfc_p[c * O_], hv[c], acc);
    out[(size_t)b * O_ + j] = acc;
  }
}

// ---------- tier-4: fp32, zero ws ----------
__global__ __launch_bounds__(1024) void rnn_fp32(
    const float* __restrict__ x,
    const float* __restrict__ Wih, const float* __restrict__ Whh,
    const float* __restrict__ bih, const float* __restrict__ bhh,
    const float* __restrict__ Wfc, const float* __restrict__ bfc,
    float* __restrict__ out) {
  __shared__ float hs[H_];
  __shared__ float xs[I_];
  const int b = blockIdx.x;
  const int j = threadIdx.x;
  const float bias = bih[j] + bhh[j];
  hs[j] = 0.f;
  const float4* wih_r = reinterpret_cast<const float4*>(Wih + (size_t)j * I_);
  const float4* whh_r = reinterpret_cast<const float4*>(Whh + (size_t)j * H_);
  const float4* xv = reinterpret_cast<const float4*>(xs);
  const float4* hv = reinterpret_cast<const float4*>(hs);
  const float* xrow = x + (size_t)b * T_ * I_;
  for (int t = 0; t < T_; ++t) {
    if (j < I_) xs[j] = xrow[t * I_ + j];
    __syncthreads();
    float acc = bias;
#pragma unroll 4
    for (int c = 0; c < I_ / 4; ++c) {
      float4 w = wih_r[c], v = xv[c];
      acc = fmaf(w.x, v.x, acc); acc = fmaf(w.y, v.y, acc);
      acc = fmaf(w.z, v.z, acc); acc = fmaf(w.w, v.w, acc);
    }
#pragma unroll 4
    for (int c = 0; c < H_ / 4; ++c) {
      float4 w = whh_r[c], v = hv[c];
      acc = fmaf(w.x, v.x, acc); acc = fmaf(w.y, v.y, acc);
      acc = fmaf(w.z, v.z, acc); acc = fmaf(w.w, v.w, acc);
    }
    float hn = tanhf(acc);
    __syncthreads();
    hs[j] = hn;
  }
  __syncthreads();
  if (j < O_) {
    float acc = bfc[j];
    const float4* wfc_r = reinterpret_cast<const float4*>(Wfc + (size_t)j * H_);
    for (int c = 0; c < H_ / 4; ++c) {
      float4 w = wfc_r[c], v = hv[c];
      acc = fmaf(w.x, v.x, acc); acc = fmaf(w.y, v.y, acc);
      acc = fmaf(w.z, v.z, acc); acc = fmaf(w.w, v.w, acc);
    }
    out[(size_t)b * O_ + j] = acc;
  }
}

extern "C" void kernel_launch(void* const* d_in, const int* in_sizes, int n_in,
                              void* d_out, int out_size, void* d_ws, size_t ws_size,
                              hipStream_t stream) {
  const float* x   = (const float*)d_in[0];
  const float* Wih = (const float*)d_in[1];
  const float* Whh = (const float*)d_in[2];
  const float* bih = (const float*)d_in[3];
  const float* bhh = (const float*)d_in[4];
  const float* Wfc = (const float*)d_in[5];
  const float* bfc = (const float*)d_in[6];
  float* out = (float*)d_out;

  const size_t n_whh = (size_t)H_ * H_;
  const size_t n_wih = (size_t)H_ * I_;
  const size_t n_wfc = (size_t)O_ * H_;
  const size_t n_x   = (size_t)B_ * T_ * I_;
  const size_t n_hseq = (size_t)T_ * NCLUST * MB * H_;
  const int thr = 256;

  // ---- tier 1 layout: whh | wih | wfcT | xbf | hseq  (~83 MB)
  {
    size_t off = 0;
    const size_t o_whh = off; off += n_whh;
    const size_t o_wih = off; off += n_wih;
    const size_t o_wfc = off; off += n_wfc;
    const size_t o_x   = off; off += n_x;
    const size_t o_hs  = off; off += n_hseq;
    const size_t need1 = off * sizeof(f16);

    if (ws_size >= need1) {
      f16* wsf   = (f16*)d_ws;
      f16* whh_h = wsf + o_whh;
      f16* wih_h = wsf + o_wih;
      f16* wfcT  = wsf + o_wfc;
      f16* xbf   = wsf + o_x;
      f16* hseq  = wsf + o_hs;

      const long n16 = (long)(n_hseq * sizeof(f16) / 16);
      init_hseq<<<4096, thr, 0, stream>>>((unsigned*)hseq, n16);
      cast_f16<<<(int)(n_whh / 4 / thr), thr, 0, stream>>>(Whh, whh_h, (int)(n_whh / 4));
      cast_f16<<<(int)(n_wih / 4 / thr), thr, 0, stream>>>(Wih, wih_h, (int)(n_wih / 4));
      cast_f16<<<(int)(n_x / 4 / thr), thr, 0, stream>>>(x, xbf, (int)(n_x / 4));
      convert_T8<<<(int)(n_wfc / 8 / thr), thr, 0, stream>>>(Wfc, wfcT, O_, H_);

      rnn6<<<NCLUST * WPC, thr, 0, stream>>>(whh_h, wih_h, xbf, bih, bhh, hseq);
      const f16* hlast = hseq + (size_t)(T_ - 1) * NCLUST * MB * H_;
      fc_head_flat<<<B_, O_, 0, stream>>>(hlast, wfcT, bfc, out);
      return;
    }
  }

  // ---- tier 3 (3 MB) / tier 4 (0)
  if (ws_size >= (n_wih + n_whh + n_wfc) * sizeof(f16)) {
    f16* wihT = (f16*)d_ws;
    f16* whhT = wihT + n_wih;
    f16* wfcT = whhT + n_whh;
    convert_T8<<<(int)((n_wih / 8 + thr - 1) / thr), thr, 0, stream>>>(Wih, wihT, H_, I_);
    convert_T8<<<(int)((n_whh / 8 + thr - 1) / thr), thr, 0, stream>>>(Whh, whhT, H_, H_);
    convert_T8<<<(int)((n_wfc / 8 + thr - 1) / thr), thr, 0, stream>>>(Wfc, wfcT, O_, H_);
    rnn_f16<<<B_, 1024, 0, stream>>>(x, wihT, whhT, bih, bhh, wfcT, bfc, out);
  } else {
    rnn_fp32<<<B_, 1024, 0, stream>>>(x, Wih, Whh, bih, bhh, Wfc, bfc, out);
  }
}